// Round 4
// baseline (370.568 us; speedup 1.0000x reference)
//
#include <hip/hip_runtime.h>
#include <cstdint>

#define D_MODEL 1024
#define D_STATE 16
#define D_INNER 2048
#define DT_RANK 64
#define BSZ 2
#define TLEN 1024
#define M_TOK (BSZ*TLEN)      // 2048 tokens
#define NXZ (2*D_INNER)       // 4096
#define NXDBL 128             // 96 padded to 128
#define TC 64
#define NCHUNK (TLEN/TC)      // 16

typedef unsigned short u16;
typedef short s16x8 __attribute__((ext_vector_type(8)));
typedef float f32x4 __attribute__((ext_vector_type(4)));

__device__ __forceinline__ u16 f2bf(float f) {
  uint32_t u = __float_as_uint(f);
  u += 0x7fffu + ((u >> 16) & 1u);
  return (u16)(u >> 16);
}

#define GLDS16(g, l) __builtin_amdgcn_global_load_lds( \
    (const __attribute__((address_space(1))) void*)(g), \
    (__attribute__((address_space(3))) void*)(l), 16, 0, 0)

// ---------------- converts ----------------
__global__ __launch_bounds__(256) void cvt_all(
    const float* __restrict__ s0, u16* __restrict__ d0, int n0,
    const float* __restrict__ s1, u16* __restrict__ d1, int n1,
    const float* __restrict__ s2, u16* __restrict__ d2, int n2,
    const float* __restrict__ s3, u16* __restrict__ d3, int n3)
{
  int total = n0 + n1 + n2 + n3;  // quad counts
  for (int i = blockIdx.x*256 + threadIdx.x; i < total; i += gridDim.x*256) {
    const float* s; u16* d; int j = i;
    if (j < n0)            { s = s0; d = d0; }
    else if ((j -= n0) < n1) { s = s1; d = d1; }
    else if ((j -= n1) < n2) { s = s2; d = d2; }
    else                   { j -= n2; s = s3; d = d3; }
    float4 v = ((const float4*)s)[j];
    u16* dst = d + (size_t)j*4;
    dst[0] = f2bf(v.x); dst[1] = f2bf(v.y); dst[2] = f2bf(v.z); dst[3] = f2bf(v.w);
  }
}

// W_x (96,2048) -> bf16 padded to (128,2048), pad rows zero
__global__ __launch_bounds__(256) void wx_pad(const float* __restrict__ wx, u16* __restrict__ dst)
{
  int i = blockIdx.x*256 + threadIdx.x;       // quad index over 128*2048/4
  int row = i >> 9;                            // 512 quads per row
  u16* d = dst + (size_t)i*4;
  if (row < 96) {
    float4 v = ((const float4*)wx)[i];
    d[0] = f2bf(v.x); d[1] = f2bf(v.y); d[2] = f2bf(v.z); d[3] = f2bf(v.w);
  } else {
    d[0] = 0; d[1] = 0; d[2] = 0; d[3] = 0;
  }
}

// ---------------- GEMM: C[m,n] = sum_k A[m,k]*B[n,k], bf16 in, f32 out ----------------
// EPI 0: plain   EPI 1: softplus(v + bias[n])
#define BM 128
#define BN 128
#define BKK 32

template<int EPI>
__global__ __launch_bounds__(256) void gemm_bt(
    const u16* __restrict__ A, const u16* __restrict__ B,
    float* __restrict__ C, int M, int N, int K,
    const float* __restrict__ bias, int kchunk)
{
  __shared__ __align__(16) u16 As[BM*BKK];
  __shared__ __align__(16) u16 Bs[BN*BKK];
  const int tid  = threadIdx.x;
  const int lane = tid & 63;
  const int wv   = tid >> 6;
  const int m0 = blockIdx.x * BM;
  const int n0 = blockIdx.y * BN;
  const int kb = blockIdx.z * kchunk;
  const int ke = kb + kchunk;
  const int wr = wv >> 1, wc = wv & 1;

  f32x4 acc[4][4];
#pragma unroll
  for (int i = 0; i < 4; i++)
#pragma unroll
    for (int j = 0; j < 4; j++) acc[i][j] = (f32x4){0.f,0.f,0.f,0.f};

  const u16* Ag = A + (size_t)(m0 + wv*32 + (lane>>2))*K + (lane&3)*8;
  const u16* Bg = B + (size_t)(n0 + wv*32 + (lane>>2))*K + (lane&3)*8;
  u16* AL0 = &As[wv*1024]; u16* AL1 = AL0 + 512;
  u16* BL0 = &Bs[wv*1024]; u16* BL1 = BL0 + 512;

  for (int k0 = kb; k0 < ke; k0 += BKK) {
    __syncthreads();
    GLDS16(Ag + k0,               AL0);
    GLDS16(Ag + (size_t)16*K + k0, AL1);
    GLDS16(Bg + k0,               BL0);
    GLDS16(Bg + (size_t)16*K + k0, BL1);
    __syncthreads();
    const int fr = lane & 15;
    const int ko = (lane >> 4) * 8;
    s16x8 af[4], bfv[4];
#pragma unroll
    for (int i = 0; i < 4; i++) af[i]  = *(const s16x8*)&As[(wr*64 + i*16 + fr)*BKK + ko];
#pragma unroll
    for (int j = 0; j < 4; j++) bfv[j] = *(const s16x8*)&Bs[(wc*64 + j*16 + fr)*BKK + ko];
#pragma unroll
    for (int i = 0; i < 4; i++)
#pragma unroll
      for (int j = 0; j < 4; j++)
        acc[i][j] = __builtin_amdgcn_mfma_f32_16x16x32_bf16(af[i], bfv[j], acc[i][j], 0, 0, 0);
  }

  float* Cb = C + (size_t)blockIdx.z * M * N;
  const int cr = (lane >> 4) * 4;
  const int cc = lane & 15;
#pragma unroll
  for (int i = 0; i < 4; i++) {
#pragma unroll
    for (int j = 0; j < 4; j++) {
      const int col = n0 + wc*64 + j*16 + cc;
      float bv = (EPI == 1) ? bias[col] : 0.f;
#pragma unroll
      for (int q = 0; q < 4; q++) {
        const int row = m0 + wr*64 + i*16 + cr + q;
        float v = acc[i][j][q];
        if (EPI == 1) { v += bv; v = (v > 20.f) ? v : log1pf(__expf(v)); }
        Cb[(size_t)row*N + col] = v;
      }
    }
  }
}

// ---------------- causal depthwise conv (k=4) + SiLU ----------------
__global__ __launch_bounds__(256) void conv_silu(
    const float* __restrict__ xz, const float* __restrict__ cw,
    const float* __restrict__ cb, float* __restrict__ xcf, u16* __restrict__ xcb)
{
  int idx = blockIdx.x*256 + threadIdx.x;    // m*2048 + d
  int d = idx & (D_INNER-1);
  int m = idx >> 11;
  int t = m & (TLEN-1);
  float acc = cb[d];
#pragma unroll
  for (int j = 0; j < 4; j++) {
    int tt = t - 3 + j;
    if (tt >= 0) acc += cw[d*4+j] * xz[(size_t)(m-3+j)*NXZ + d];
  }
  float sg = 1.f/(1.f + __expf(-acc));
  float v = acc * sg;
  xcf[idx] = v;
  xcb[idx] = f2bf(v);
}

// ---------------- reduce split-K partials of GEMM2, emit dt_low bf16 ----------------
__global__ __launch_bounds__(256) void prep(
    const float* __restrict__ part, float* __restrict__ xdbl, u16* __restrict__ dtl)
{
  int idx = blockIdx.x*256 + threadIdx.x;    // 2048*128
  float s = 0.f;
#pragma unroll
  for (int c = 0; c < 8; c++) s += part[(size_t)c*M_TOK*NXDBL + idx];
  xdbl[idx] = s;
  int col = idx & 127;
  if (col < DT_RANK) {
    int m = idx >> 7;
    dtl[(size_t)m*DT_RANK + col] = f2bf(s);
  }
}

// ---------------- selective scan, chunked (pass1: per-chunk P,S) ----------------
__global__ __launch_bounds__(256) void scan1(
    const float* __restrict__ dt, const float* __restrict__ xc,
    const float* __restrict__ xdbl, const float* __restrict__ A_log,
    float* __restrict__ P, float* __restrict__ S)
{
  int bid = blockIdx.x;
  int dblk = bid & 127;
  int b = (bid >> 7) & 1;
  int chunk = bid >> 8;
  int lane = threadIdx.x & 63;
  int wv = threadIdx.x >> 6;
  int dl = lane >> 4;
  int n = lane & 15;
  int d = dblk*16 + wv*4 + dl;
  float Ac = -__expf(A_log[d*D_STATE + n]);
  int m0 = b*TLEN + chunk*TC;
  float h = 0.f, p = 1.f;
  for (int i = 0; i < TC; i++) {
    size_t m = m0 + i;
    float dtv = dt[m*D_INNER + d];
    float xv  = xc[m*D_INNER + d];
    float Bv  = xdbl[m*NXDBL + DT_RANK + n];
    float dA = __expf(dtv*Ac);
    h = fmaf(dA, h, dtv*Bv*xv);
    p *= dA;
  }
  size_t o = ((size_t)((chunk*2 + b)*D_INNER + d))*D_STATE + n;
  P[o] = p; S[o] = h;
}

// ---------------- chunk-prefix stitch ----------------
__global__ __launch_bounds__(256) void stitch(
    const float* __restrict__ P, const float* __restrict__ S, float* __restrict__ Hin)
{
  int idx = blockIdx.x*256 + threadIdx.x;   // (b*2048+d)*16+n, 65536 total
  const int stride = 2*D_INNER*D_STATE;
  float h = 0.f;
#pragma unroll
  for (int c = 0; c < NCHUNK; c++) {
    Hin[(size_t)c*stride + idx] = h;
    h = fmaf(P[(size_t)c*stride + idx], h, S[(size_t)c*stride + idx]);
  }
}

// ---------------- scan pass2: recompute + y, fused silu(z)*y + D*x, bf16 out ----------------
__global__ __launch_bounds__(256) void scan2(
    const float* __restrict__ dt, const float* __restrict__ xc,
    const float* __restrict__ xdbl, const float* __restrict__ A_log,
    const float* __restrict__ Hin, const float* __restrict__ xz,
    const float* __restrict__ Dp, u16* __restrict__ yb)
{
  int bid = blockIdx.x;
  int dblk = bid & 127;
  int b = (bid >> 7) & 1;
  int chunk = bid >> 8;
  int lane = threadIdx.x & 63;
  int wv = threadIdx.x >> 6;
  int dl = lane >> 4;
  int n = lane & 15;
  int d = dblk*16 + wv*4 + dl;
  float Ac = -__expf(A_log[d*D_STATE + n]);
  float h = Hin[((size_t)((chunk*2 + b)*D_INNER + d))*D_STATE + n];
  int m0 = b*TLEN + chunk*TC;
  float Dv = Dp[d];
  for (int i = 0; i < TC; i++) {
    size_t m = m0 + i;
    float dtv = dt[m*D_INNER + d];
    float xv  = xc[m*D_INNER + d];
    float Bv  = xdbl[m*NXDBL + DT_RANK + n];
    float Cv  = xdbl[m*NXDBL + DT_RANK + D_STATE + n];
    float dA = __expf(dtv*Ac);
    h = fmaf(dA, h, dtv*Bv*xv);
    float yc = h*Cv;
    yc += __shfl_xor(yc, 1);
    yc += __shfl_xor(yc, 2);
    yc += __shfl_xor(yc, 4);
    yc += __shfl_xor(yc, 8);
    if (n == 0) {
      float z = xz[m*NXZ + D_INNER + d];
      float sz = z/(1.f + __expf(-z));
      float yf = fmaf(yc, sz, Dv*xv);
      yb[m*D_INNER + d] = f2bf(yf);
    }
  }
}

// ---------------- launcher ----------------
extern "C" void kernel_launch(void* const* d_in, const int* in_sizes, int n_in,
                              void* d_out, int out_size, void* d_ws, size_t ws_size,
                              hipStream_t stream)
{
  const float* x     = (const float*)d_in[0];
  const float* W_in  = (const float*)d_in[1];
  const float* convw = (const float*)d_in[2];
  const float* convb = (const float*)d_in[3];
  const float* W_x   = (const float*)d_in[4];
  const float* W_dt  = (const float*)d_in[5];
  const float* b_dt  = (const float*)d_in[6];
  const float* A_log = (const float*)d_in[7];
  const float* Dp    = (const float*)d_in[8];
  const float* W_out = (const float*)d_in[9];
  float* out = (float*)d_out;

  char* w = (char*)d_ws;
  size_t o = 0;
  auto alloc = [&](size_t bytes) { char* p = w + o; o = (o + bytes + 255) & ~(size_t)255; return p; };
  u16*   xb   = (u16*)  alloc((size_t)M_TOK*D_MODEL*2);
  u16*   Wib  = (u16*)  alloc((size_t)NXZ*D_MODEL*2);
  u16*   Wxb  = (u16*)  alloc((size_t)NXDBL*D_INNER*2);
  u16*   Wdtb = (u16*)  alloc((size_t)D_INNER*DT_RANK*2);
  u16*   Wob  = (u16*)  alloc((size_t)D_MODEL*D_INNER*2);
  float* xzbuf= (float*)alloc((size_t)M_TOK*NXZ*4);
  float* xcf  = (float*)alloc((size_t)M_TOK*D_INNER*4);
  u16*   xcb  = (u16*)  alloc((size_t)M_TOK*D_INNER*2);
  float* part = (float*)alloc((size_t)8*M_TOK*NXDBL*4);
  float* xdbl = (float*)alloc((size_t)M_TOK*NXDBL*4);
  u16*   dtl  = (u16*)  alloc((size_t)M_TOK*DT_RANK*2);
  float* dtm  = (float*)alloc((size_t)M_TOK*D_INNER*4);
  float* Pb   = (float*)alloc((size_t)NCHUNK*2*D_INNER*D_STATE*4);
  float* Sb   = (float*)alloc((size_t)NCHUNK*2*D_INNER*D_STATE*4);
  float* Hin  = (float*)alloc((size_t)NCHUNK*2*D_INNER*D_STATE*4);
  u16*   yb   = (u16*)  alloc((size_t)M_TOK*D_INNER*2);
  (void)ws_size; (void)n_in; (void)in_sizes; (void)out_size;

  // 1. weight/input converts to bf16
  cvt_all<<<2048,256,0,stream>>>(x, xb, (M_TOK*D_MODEL)/4,
                                 W_in, Wib, (NXZ*D_MODEL)/4,
                                 W_dt, Wdtb, (D_INNER*DT_RANK)/4,
                                 W_out, Wob, (D_MODEL*D_INNER)/4);
  wx_pad<<<(NXDBL*D_INNER/4)/256,256,0,stream>>>(W_x, Wxb);
  // 2. xz = x @ W_in^T
  gemm_bt<0><<<dim3(M_TOK/BM, NXZ/BN, 1),256,0,stream>>>(xb, Wib, xzbuf, M_TOK, NXZ, D_MODEL, nullptr, D_MODEL);
  // 3. conv + silu
  conv_silu<<<(M_TOK*D_INNER)/256,256,0,stream>>>(xzbuf, convw, convb, xcf, xcb);
  // 4. x_dbl = x_conv @ W_x^T (split-K 8)
  gemm_bt<0><<<dim3(M_TOK/BM, 1, 8),256,0,stream>>>(xcb, Wxb, part, M_TOK, NXDBL, D_INNER, nullptr, D_INNER/8);
  prep<<<(M_TOK*NXDBL)/256,256,0,stream>>>(part, xdbl, dtl);
  // 5. dt = softplus(dt_low @ W_dt^T + b_dt)
  gemm_bt<1><<<dim3(M_TOK/BM, D_INNER/BN, 1),256,0,stream>>>(dtl, Wdtb, dtm, M_TOK, D_INNER, DT_RANK, b_dt, DT_RANK);
  // 6. chunked scan
  scan1<<<128*2*NCHUNK,256,0,stream>>>(dtm, xcf, xdbl, A_log, Pb, Sb);
  stitch<<<(2*D_INNER*D_STATE)/256,256,0,stream>>>(Pb, Sb, Hin);
  scan2<<<128*2*NCHUNK,256,0,stream>>>(dtm, xcf, xdbl, A_log, Hin, xzbuf, Dp, yb);
  // 7. out = y @ W_out^T
  gemm_bt<0><<<dim3(M_TOK/BM, D_MODEL/BN, 1),256,0,stream>>>(yb, Wob, out, M_TOK, D_MODEL, D_INNER, nullptr, D_INNER);
}

// Round 6
// 288.258 us; speedup vs baseline: 1.2855x; 1.2855x over previous
//
#include <hip/hip_runtime.h>
#include <cstdint>

#define D_MODEL 1024
#define D_STATE 16
#define D_INNER 2048
#define DT_RANK 64
#define BSZ 2
#define TLEN 1024
#define M_TOK (BSZ*TLEN)      // 2048 tokens
#define NXZ (2*D_INNER)       // 4096
#define NXDBL 128             // 96 padded to 128
#define TC 16
#define NCHUNK (TLEN/TC)      // 64

typedef unsigned short u16;
typedef short s16x8 __attribute__((ext_vector_type(8)));
typedef float f32x4 __attribute__((ext_vector_type(4)));

__device__ __forceinline__ u16 f2bf(float f) {
  uint32_t u = __float_as_uint(f);
  u += 0x7fffu + ((u >> 16) & 1u);
  return (u16)(u >> 16);
}

#define GLDS16(g, l) __builtin_amdgcn_global_load_lds( \
    (const __attribute__((address_space(1))) void*)(g), \
    (__attribute__((address_space(3))) void*)(l), 16, 0, 0)

// ---------------- converts ----------------
__global__ __launch_bounds__(256) void cvt_all(
    const float* __restrict__ s0, u16* __restrict__ d0, int n0,
    const float* __restrict__ s1, u16* __restrict__ d1, int n1,
    const float* __restrict__ s2, u16* __restrict__ d2, int n2,
    const float* __restrict__ s3, u16* __restrict__ d3, int n3)
{
  int total = n0 + n1 + n2 + n3;  // quad counts
  for (int i = blockIdx.x*256 + threadIdx.x; i < total; i += gridDim.x*256) {
    const float* s; u16* d; int j = i;
    if (j < n0)            { s = s0; d = d0; }
    else if ((j -= n0) < n1) { s = s1; d = d1; }
    else if ((j -= n1) < n2) { s = s2; d = d2; }
    else                   { j -= n2; s = s3; d = d3; }
    float4 v = ((const float4*)s)[j];
    u16* dst = d + (size_t)j*4;
    dst[0] = f2bf(v.x); dst[1] = f2bf(v.y); dst[2] = f2bf(v.z); dst[3] = f2bf(v.w);
  }
}

// W_x (96,2048) -> bf16 padded to (128,2048), pad rows zero
__global__ __launch_bounds__(256) void wx_pad(const float* __restrict__ wx, u16* __restrict__ dst)
{
  int i = blockIdx.x*256 + threadIdx.x;       // quad index over 128*2048/4
  int row = i >> 9;                            // 512 quads per row
  u16* d = dst + (size_t)i*4;
  if (row < 96) {
    float4 v = ((const float4*)wx)[i];
    d[0] = f2bf(v.x); d[1] = f2bf(v.y); d[2] = f2bf(v.z); d[3] = f2bf(v.w);
  } else {
    d[0] = 0; d[1] = 0; d[2] = 0; d[3] = 0;
  }
}

// ---------------- GEMM: C[m,n] = sum_k A[m,k]*B[n,k], bf16 in, f32 out ----------------
// EPI 0: plain   EPI 1: softplus(v + bias[n])
#define BM 128
#define BN 128
#define BKK 32

template<int EPI>
__global__ __launch_bounds__(256) void gemm_bt(
    const u16* __restrict__ A, const u16* __restrict__ B,
    float* __restrict__ C, int M, int N, int K,
    const float* __restrict__ bias, int kchunk)
{
  __shared__ __align__(16) u16 As[BM*BKK];
  __shared__ __align__(16) u16 Bs[BN*BKK];
  const int tid  = threadIdx.x;
  const int lane = tid & 63;
  const int wv   = tid >> 6;
  const int m0 = blockIdx.x * BM;
  const int n0 = blockIdx.y * BN;
  const int kb = blockIdx.z * kchunk;
  const int ke = kb + kchunk;
  const int wr = wv >> 1, wc = wv & 1;

  f32x4 acc[4][4];
#pragma unroll
  for (int i = 0; i < 4; i++)
#pragma unroll
    for (int j = 0; j < 4; j++) acc[i][j] = (f32x4){0.f,0.f,0.f,0.f};

  const u16* Ag = A + (size_t)(m0 + wv*32 + (lane>>2))*K + (lane&3)*8;
  const u16* Bg = B + (size_t)(n0 + wv*32 + (lane>>2))*K + (lane&3)*8;
  u16* AL0 = &As[wv*1024]; u16* AL1 = AL0 + 512;
  u16* BL0 = &Bs[wv*1024]; u16* BL1 = BL0 + 512;

  for (int k0 = kb; k0 < ke; k0 += BKK) {
    __syncthreads();
    GLDS16(Ag + k0,               AL0);
    GLDS16(Ag + (size_t)16*K + k0, AL1);
    GLDS16(Bg + k0,               BL0);
    GLDS16(Bg + (size_t)16*K + k0, BL1);
    __syncthreads();
    const int fr = lane & 15;
    const int ko = (lane >> 4) * 8;
    s16x8 af[4], bfv[4];
#pragma unroll
    for (int i = 0; i < 4; i++) af[i]  = *(const s16x8*)&As[(wr*64 + i*16 + fr)*BKK + ko];
#pragma unroll
    for (int j = 0; j < 4; j++) bfv[j] = *(const s16x8*)&Bs[(wc*64 + j*16 + fr)*BKK + ko];
#pragma unroll
    for (int i = 0; i < 4; i++)
#pragma unroll
      for (int j = 0; j < 4; j++)
        acc[i][j] = __builtin_amdgcn_mfma_f32_16x16x32_bf16(af[i], bfv[j], acc[i][j], 0, 0, 0);
  }

  float* Cb = C + (size_t)blockIdx.z * M * N;
  const int cr = (lane >> 4) * 4;
  const int cc = lane & 15;
#pragma unroll
  for (int i = 0; i < 4; i++) {
#pragma unroll
    for (int j = 0; j < 4; j++) {
      const int col = n0 + wc*64 + j*16 + cc;
      float bv = (EPI == 1) ? bias[col] : 0.f;
#pragma unroll
      for (int q = 0; q < 4; q++) {
        const int row = m0 + wr*64 + i*16 + cr + q;
        float v = acc[i][j][q];
        if (EPI == 1) { v += bv; v = (v > 20.f) ? v : log1pf(__expf(v)); }
        Cb[(size_t)row*N + col] = v;
      }
    }
  }
}

// ---------------- causal depthwise conv (k=4) + SiLU ----------------
__global__ __launch_bounds__(256) void conv_silu(
    const float* __restrict__ xz, const float* __restrict__ cw,
    const float* __restrict__ cb, float* __restrict__ xcf, u16* __restrict__ xcb)
{
  int idx = blockIdx.x*256 + threadIdx.x;    // m*2048 + d
  int d = idx & (D_INNER-1);
  int m = idx >> 11;
  int t = m & (TLEN-1);
  float acc = cb[d];
#pragma unroll
  for (int j = 0; j < 4; j++) {
    int tt = t - 3 + j;
    if (tt >= 0) acc += cw[d*4+j] * xz[(size_t)(m-3+j)*NXZ + d];
  }
  float sg = 1.f/(1.f + __expf(-acc));
  float v = acc * sg;
  xcf[idx] = v;
  xcb[idx] = f2bf(v);
}

// ---------------- reduce split-K partials of GEMM2, emit dt_low bf16 ----------------
__global__ __launch_bounds__(256) void prep(
    const float* __restrict__ part, float* __restrict__ xdbl, u16* __restrict__ dtl)
{
  int idx = blockIdx.x*256 + threadIdx.x;    // 2048*128
  float s = 0.f;
#pragma unroll
  for (int c = 0; c < 8; c++) s += part[(size_t)c*M_TOK*NXDBL + idx];
  xdbl[idx] = s;
  int col = idx & 127;
  if (col < DT_RANK) {
    int m = idx >> 7;
    dtl[(size_t)m*DT_RANK + col] = f2bf(s);
  }
}

// ---------------- selective scan pass1: per-chunk (P, S), d-per-lane, 16 states in regs ----
__global__ __launch_bounds__(256) void scan1(
    const float* __restrict__ dt, const float* __restrict__ xc,
    const float* __restrict__ xdbl, const float* __restrict__ A_log,
    float* __restrict__ P, float* __restrict__ S)
{
  const int bid = blockIdx.x;        // dblk(8) | b(2) | chunk(64)
  const int dblk = bid & 7;
  const int b = (bid >> 3) & 1;
  const int chunk = bid >> 4;
  const int d = dblk*256 + threadIdx.x;

  float Ac[16];
  {
    const float4* Ap = (const float4*)(A_log + (size_t)d*D_STATE);
#pragma unroll
    for (int q = 0; q < 4; q++) {
      float4 v = Ap[q];
      Ac[q*4+0] = -__expf(v.x); Ac[q*4+1] = -__expf(v.y);
      Ac[q*4+2] = -__expf(v.z); Ac[q*4+3] = -__expf(v.w);
    }
  }
  float h[16], p[16];
#pragma unroll
  for (int n = 0; n < 16; n++) { h[n] = 0.f; p[n] = 1.f; }

  const int m0 = b*TLEN + chunk*TC;
  for (int i = 0; i < TC; i++) {
    const size_t m = m0 + i;
    float dtv = dt[m*D_INNER + d];
    float xv  = xc[m*D_INNER + d];
    float dbx = dtv * xv;
    const float4* Bp = (const float4*)(xdbl + m*NXDBL + DT_RANK);
    float4 B0 = Bp[0], B1 = Bp[1], B2 = Bp[2], B3 = Bp[3];
    float Bv[16] = {B0.x,B0.y,B0.z,B0.w, B1.x,B1.y,B1.z,B1.w,
                    B2.x,B2.y,B2.z,B2.w, B3.x,B3.y,B3.z,B3.w};
#pragma unroll
    for (int n = 0; n < 16; n++) {
      float dA = __expf(dtv * Ac[n]);
      h[n] = fmaf(dA, h[n], dbx * Bv[n]);
      p[n] *= dA;
    }
  }
  size_t o = ((size_t)((chunk*2 + b)*D_INNER + d))*D_STATE;
  float4* Pp = (float4*)(P + o);
  float4* Sp = (float4*)(S + o);
#pragma unroll
  for (int q = 0; q < 4; q++) {
    Pp[q] = (float4){p[q*4+0], p[q*4+1], p[q*4+2], p[q*4+3]};
    Sp[q] = (float4){h[q*4+0], h[q*4+1], h[q*4+2], h[q*4+3]};
  }
}

// ---------------- chunk-prefix stitch (in place: S[c] <- prefix state before chunk c) ----
__global__ __launch_bounds__(256) void stitch(
    const float* __restrict__ P, float* __restrict__ S)
{
  int idx = blockIdx.x*256 + threadIdx.x;   // (b*2048+d)*16+n, 65536 total
  const size_t stride = 2*D_INNER*D_STATE;
  float h = 0.f;
#pragma unroll 4
  for (int c = 0; c < NCHUNK; c++) {
    size_t o = (size_t)c*stride + idx;
    float p = P[o], s = S[o];
    S[o] = h;
    h = fmaf(p, h, s);
  }
}

// ---------------- scan pass2: recompute + y, fused silu(z)*y + D*x, bf16 out ----------------
__global__ __launch_bounds__(256) void scan2(
    const float* __restrict__ dt, const float* __restrict__ xc,
    const float* __restrict__ xdbl, const float* __restrict__ A_log,
    const float* __restrict__ Hpref, const float* __restrict__ xz,
    const float* __restrict__ Dp, u16* __restrict__ yb)
{
  const int bid = blockIdx.x;
  const int dblk = bid & 7;
  const int b = (bid >> 3) & 1;
  const int chunk = bid >> 4;
  const int d = dblk*256 + threadIdx.x;

  float Ac[16];
  {
    const float4* Ap = (const float4*)(A_log + (size_t)d*D_STATE);
#pragma unroll
    for (int q = 0; q < 4; q++) {
      float4 v = Ap[q];
      Ac[q*4+0] = -__expf(v.x); Ac[q*4+1] = -__expf(v.y);
      Ac[q*4+2] = -__expf(v.z); Ac[q*4+3] = -__expf(v.w);
    }
  }
  float h[16];
  {
    size_t o = ((size_t)((chunk*2 + b)*D_INNER + d))*D_STATE;
    const float4* Hp = (const float4*)(Hpref + o);
#pragma unroll
    for (int q = 0; q < 4; q++) {
      float4 v = Hp[q];
      h[q*4+0] = v.x; h[q*4+1] = v.y; h[q*4+2] = v.z; h[q*4+3] = v.w;
    }
  }
  const float Dv = Dp[d];
  const int m0 = b*TLEN + chunk*TC;
  for (int i = 0; i < TC; i++) {
    const size_t m = m0 + i;
    float dtv = dt[m*D_INNER + d];
    float xv  = xc[m*D_INNER + d];
    float dbx = dtv * xv;
    const float4* Bp = (const float4*)(xdbl + m*NXDBL + DT_RANK);
    float4 B0 = Bp[0], B1 = Bp[1], B2 = Bp[2], B3 = Bp[3];
    const float4* Cp = (const float4*)(xdbl + m*NXDBL + DT_RANK + D_STATE);
    float4 C0 = Cp[0], C1 = Cp[1], C2 = Cp[2], C3 = Cp[3];
    float Bv[16] = {B0.x,B0.y,B0.z,B0.w, B1.x,B1.y,B1.z,B1.w,
                    B2.x,B2.y,B2.z,B2.w, B3.x,B3.y,B3.z,B3.w};
    float Cv[16] = {C0.x,C0.y,C0.z,C0.w, C1.x,C1.y,C1.z,C1.w,
                    C2.x,C2.y,C2.z,C2.w, C3.x,C3.y,C3.z,C3.w};
    float y = 0.f;
#pragma unroll
    for (int n = 0; n < 16; n++) {
      float dA = __expf(dtv * Ac[n]);
      h[n] = fmaf(dA, h[n], dbx * Bv[n]);
      y = fmaf(h[n], Cv[n], y);
    }
    float z = xz[m*NXZ + D_INNER + d];
    float sz = z/(1.f + __expf(-z));
    yb[m*D_INNER + d] = f2bf(fmaf(y, sz, Dv*xv));
  }
}

// ---------------- launcher ----------------
extern "C" void kernel_launch(void* const* d_in, const int* in_sizes, int n_in,
                              void* d_out, int out_size, void* d_ws, size_t ws_size,
                              hipStream_t stream)
{
  const float* x     = (const float*)d_in[0];
  const float* W_in  = (const float*)d_in[1];
  const float* convw = (const float*)d_in[2];
  const float* convb = (const float*)d_in[3];
  const float* W_x   = (const float*)d_in[4];
  const float* W_dt  = (const float*)d_in[5];
  const float* b_dt  = (const float*)d_in[6];
  const float* A_log = (const float*)d_in[7];
  const float* Dp    = (const float*)d_in[8];
  const float* W_out = (const float*)d_in[9];
  float* out = (float*)d_out;

  char* w = (char*)d_ws;
  size_t o = 0;
  auto alloc = [&](size_t bytes) { char* p = w + o; o = (o + bytes + 255) & ~(size_t)255; return p; };
  u16*   xb   = (u16*)  alloc((size_t)M_TOK*D_MODEL*2);
  u16*   Wib  = (u16*)  alloc((size_t)NXZ*D_MODEL*2);
  u16*   Wxb  = (u16*)  alloc((size_t)NXDBL*D_INNER*2);
  u16*   Wdtb = (u16*)  alloc((size_t)D_INNER*DT_RANK*2);
  u16*   Wob  = (u16*)  alloc((size_t)D_MODEL*D_INNER*2);
  float* xzbuf= (float*)alloc((size_t)M_TOK*NXZ*4);
  float* xcf  = (float*)alloc((size_t)M_TOK*D_INNER*4);
  u16*   xcb  = (u16*)  alloc((size_t)M_TOK*D_INNER*2);
  float* part = (float*)alloc((size_t)8*M_TOK*NXDBL*4);
  float* xdbl = (float*)alloc((size_t)M_TOK*NXDBL*4);
  u16*   dtl  = (u16*)  alloc((size_t)M_TOK*DT_RANK*2);
  float* dtm  = (float*)alloc((size_t)M_TOK*D_INNER*4);
  float* Pb   = (float*)alloc((size_t)NCHUNK*2*D_INNER*D_STATE*4);
  float* Sb   = (float*)alloc((size_t)NCHUNK*2*D_INNER*D_STATE*4);
  u16*   yb   = (u16*)  alloc((size_t)M_TOK*D_INNER*2);
  (void)ws_size; (void)n_in; (void)in_sizes; (void)out_size;

  // 1. weight/input converts to bf16
  cvt_all<<<2048,256,0,stream>>>(x, xb, (M_TOK*D_MODEL)/4,
                                 W_in, Wib, (NXZ*D_MODEL)/4,
                                 W_dt, Wdtb, (D_INNER*DT_RANK)/4,
                                 W_out, Wob, (D_MODEL*D_INNER)/4);
  wx_pad<<<(NXDBL*D_INNER/4)/256,256,0,stream>>>(W_x, Wxb);
  // 2. xz = x @ W_in^T
  gemm_bt<0><<<dim3(M_TOK/BM, NXZ/BN, 1),256,0,stream>>>(xb, Wib, xzbuf, M_TOK, NXZ, D_MODEL, nullptr, D_MODEL);
  // 3. conv + silu
  conv_silu<<<(M_TOK*D_INNER)/256,256,0,stream>>>(xzbuf, convw, convb, xcf, xcb);
  // 4. x_dbl = x_conv @ W_x^T (split-K 8)
  gemm_bt<0><<<dim3(M_TOK/BM, 1, 8),256,0,stream>>>(xcb, Wxb, part, M_TOK, NXDBL, D_INNER, nullptr, D_INNER/8);
  prep<<<(M_TOK*NXDBL)/256,256,0,stream>>>(part, xdbl, dtl);
  // 5. dt = softplus(dt_low @ W_dt^T + b_dt)
  gemm_bt<1><<<dim3(M_TOK/BM, D_INNER/BN, 1),256,0,stream>>>(dtl, Wdtb, dtm, M_TOK, D_INNER, DT_RANK, b_dt, DT_RANK);
  // 6. chunked scan (d-per-lane): pass1 -> stitch (in-place prefix into Sb) -> pass2
  scan1<<<8*2*NCHUNK,256,0,stream>>>(dtm, xcf, xdbl, A_log, Pb, Sb);
  stitch<<<(2*D_INNER*D_STATE)/256,256,0,stream>>>(Pb, Sb);
  scan2<<<8*2*NCHUNK,256,0,stream>>>(dtm, xcf, xdbl, A_log, Sb, xzbuf, Dp, yb);
  // 7. out = y @ W_out^T
  gemm_bt<0><<<dim3(M_TOK/BM, D_MODEL/BN, 1),256,0,stream>>>(yb, Wob, out, M_TOK, D_MODEL, D_INNER, nullptr, D_INNER);
}

// Round 7
// 267.416 us; speedup vs baseline: 1.3857x; 1.0779x over previous
//
#include <hip/hip_runtime.h>
#include <cstdint>

#define D_MODEL 1024
#define D_STATE 16
#define D_INNER 2048
#define DT_RANK 64
#define BSZ 2
#define TLEN 1024
#define M_TOK (BSZ*TLEN)      // 2048 tokens
#define NXZ (2*D_INNER)       // 4096
#define NXDBL 128             // 96 padded to 128
#define TC 16
#define NCHUNK (TLEN/TC)      // 64

typedef unsigned short u16;
typedef short s16x8 __attribute__((ext_vector_type(8)));
typedef float f32x4 __attribute__((ext_vector_type(4)));

__device__ __forceinline__ u16 f2bf(float f) {
  uint32_t u = __float_as_uint(f);
  u += 0x7fffu + ((u >> 16) & 1u);
  return (u16)(u >> 16);
}

#define GLDS16(g, l) __builtin_amdgcn_global_load_lds( \
    (const __attribute__((address_space(1))) void*)(g), \
    (__attribute__((address_space(3))) void*)(l), 16, 0, 0)

// ---------------- converts ----------------
__global__ __launch_bounds__(256) void cvt_all(
    const float* __restrict__ s0, u16* __restrict__ d0, int n0,
    const float* __restrict__ s1, u16* __restrict__ d1, int n1,
    const float* __restrict__ s2, u16* __restrict__ d2, int n2,
    const float* __restrict__ s3, u16* __restrict__ d3, int n3)
{
  int total = n0 + n1 + n2 + n3;  // quad counts
  for (int i = blockIdx.x*256 + threadIdx.x; i < total; i += gridDim.x*256) {
    const float* s; u16* d; int j = i;
    if (j < n0)            { s = s0; d = d0; }
    else if ((j -= n0) < n1) { s = s1; d = d1; }
    else if ((j -= n1) < n2) { s = s2; d = d2; }
    else                   { j -= n2; s = s3; d = d3; }
    float4 v = ((const float4*)s)[j];
    u16* dst = d + (size_t)j*4;
    dst[0] = f2bf(v.x); dst[1] = f2bf(v.y); dst[2] = f2bf(v.z); dst[3] = f2bf(v.w);
  }
}

// W_x (96,2048) -> bf16 padded to (128,2048), pad rows zero
__global__ __launch_bounds__(256) void wx_pad(const float* __restrict__ wx, u16* __restrict__ dst)
{
  int i = blockIdx.x*256 + threadIdx.x;       // quad index over 128*2048/4
  int row = i >> 9;                            // 512 quads per row
  u16* d = dst + (size_t)i*4;
  if (row < 96) {
    float4 v = ((const float4*)wx)[i];
    d[0] = f2bf(v.x); d[1] = f2bf(v.y); d[2] = f2bf(v.z); d[3] = f2bf(v.w);
  } else {
    d[0] = 0; d[1] = 0; d[2] = 0; d[3] = 0;
  }
}

// ---------------- GEMM: C[m,n] = sum_k A[m,k]*B[n,k], bf16 in, f32 out ----------------
// Tile = (32*FM) x (32*FN); 4 waves in a 2x2 grid, each owns (FM*16) x (FN*16).
// EPI 0: plain   EPI 1: softplus(v + bias[n])
template<int EPI, int FM, int FN>
__global__ __launch_bounds__(256) void gemm_bt(
    const u16* __restrict__ A, const u16* __restrict__ B,
    float* __restrict__ C, int M, int N, int K,
    const float* __restrict__ bias, int kchunk)
{
  constexpr int BMt = FM*32;
  constexpr int BNt = FN*32;
  constexpr int AOPS = BMt/16;          // 16-row staging blocks for A
  constexpr int TOPS = (BMt+BNt)/16;    // total staging blocks
  constexpr int NOPS = TOPS/4;          // per wave
  __shared__ __align__(16) u16 As[BMt*32];
  __shared__ __align__(16) u16 Bs[BNt*32];
  const int tid  = threadIdx.x;
  const int lane = tid & 63;
  const int wv   = tid >> 6;
  const int m0 = blockIdx.x * BMt;
  const int n0 = blockIdx.y * BNt;
  const int kb = blockIdx.z * kchunk;
  const int ke = kb + kchunk;
  const int wr = wv >> 1, wc = wv & 1;

  f32x4 acc[FM][FN];
#pragma unroll
  for (int i = 0; i < FM; i++)
#pragma unroll
    for (int j = 0; j < FN; j++) acc[i][j] = (f32x4){0.f,0.f,0.f,0.f};

  // staging assignments (wave-uniform dst, per-lane src)
  const int rl = lane >> 2;
  const int c8 = (lane & 3) * 8;
  const u16* srcs[NOPS];
  u16* dsts[NOPS];
#pragma unroll
  for (int t = 0; t < NOPS; t++) {
    int op = wv + t*4;
    if (op < AOPS) {
      srcs[t] = A + (size_t)(m0 + op*16 + rl)*K + c8;
      dsts[t] = &As[op*512];
    } else {
      srcs[t] = B + (size_t)(n0 + (op-AOPS)*16 + rl)*K + c8;
      dsts[t] = &Bs[(op-AOPS)*512];
    }
  }

  const int fr = lane & 15;
  const int ko = (lane >> 4) * 8;
  for (int k0 = kb; k0 < ke; k0 += 32) {
    __syncthreads();
#pragma unroll
    for (int t = 0; t < NOPS; t++) GLDS16(srcs[t] + k0, dsts[t]);
    __syncthreads();
    s16x8 af[FM], bfv[FN];
#pragma unroll
    for (int i = 0; i < FM; i++) af[i]  = *(const s16x8*)&As[(wr*FM*16 + i*16 + fr)*32 + ko];
#pragma unroll
    for (int j = 0; j < FN; j++) bfv[j] = *(const s16x8*)&Bs[(wc*FN*16 + j*16 + fr)*32 + ko];
#pragma unroll
    for (int i = 0; i < FM; i++)
#pragma unroll
      for (int j = 0; j < FN; j++)
        acc[i][j] = __builtin_amdgcn_mfma_f32_16x16x32_bf16(af[i], bfv[j], acc[i][j], 0, 0, 0);
  }

  float* Cb = C + (size_t)blockIdx.z * M * N;
  const int cr = (lane >> 4) * 4;
  const int cc = lane & 15;
#pragma unroll
  for (int i = 0; i < FM; i++) {
#pragma unroll
    for (int j = 0; j < FN; j++) {
      const int col = n0 + (wc*FN + j)*16 + cc;
      float bv = (EPI == 1) ? bias[col] : 0.f;
#pragma unroll
      for (int q = 0; q < 4; q++) {
        const int row = m0 + (wr*FM + i)*16 + cr + q;
        float v = acc[i][j][q];
        if (EPI == 1) { v += bv; v = (v > 20.f) ? v : log1pf(__expf(v)); }
        Cb[(size_t)row*N + col] = v;
      }
    }
  }
}

// ---------------- causal depthwise conv (k=4) + SiLU ----------------
__global__ __launch_bounds__(256) void conv_silu(
    const float* __restrict__ xz, const float* __restrict__ cw,
    const float* __restrict__ cb, float* __restrict__ xcf, u16* __restrict__ xcb)
{
  int idx = blockIdx.x*256 + threadIdx.x;    // m*2048 + d
  int d = idx & (D_INNER-1);
  int m = idx >> 11;
  int t = m & (TLEN-1);
  float acc = cb[d];
#pragma unroll
  for (int j = 0; j < 4; j++) {
    int tt = t - 3 + j;
    if (tt >= 0) acc += cw[d*4+j] * xz[(size_t)(m-3+j)*NXZ + d];
  }
  float sg = 1.f/(1.f + __expf(-acc));
  float v = acc * sg;
  xcf[idx] = v;
  xcb[idx] = f2bf(v);
}

// ---------------- reduce split-K partials of GEMM2, emit dt_low bf16 ----------------
__global__ __launch_bounds__(256) void prep(
    const float* __restrict__ part, float* __restrict__ xdbl, u16* __restrict__ dtl)
{
  int idx = blockIdx.x*256 + threadIdx.x;    // 2048*128
  float s = 0.f;
#pragma unroll
  for (int c = 0; c < 8; c++) s += part[(size_t)c*M_TOK*NXDBL + idx];
  xdbl[idx] = s;
  int col = idx & 127;
  if (col < DT_RANK) {
    int m = idx >> 7;
    dtl[(size_t)m*DT_RANK + col] = f2bf(s);
  }
}

// ---------------- selective scan pass1: per-chunk (P, S), d-per-lane, 16 states in regs ----
__global__ __launch_bounds__(256) void scan1(
    const float* __restrict__ dt, const float* __restrict__ xc,
    const float* __restrict__ xdbl, const float* __restrict__ A_log,
    float* __restrict__ P, float* __restrict__ S)
{
  const int bid = blockIdx.x;        // dblk(8) | b(2) | chunk(64)
  const int dblk = bid & 7;
  const int b = (bid >> 3) & 1;
  const int chunk = bid >> 4;
  const int d = dblk*256 + threadIdx.x;

  float Ac[16];
  {
    const float4* Ap = (const float4*)(A_log + (size_t)d*D_STATE);
#pragma unroll
    for (int q = 0; q < 4; q++) {
      float4 v = Ap[q];
      Ac[q*4+0] = -__expf(v.x); Ac[q*4+1] = -__expf(v.y);
      Ac[q*4+2] = -__expf(v.z); Ac[q*4+3] = -__expf(v.w);
    }
  }
  float h[16], p[16];
#pragma unroll
  for (int n = 0; n < 16; n++) { h[n] = 0.f; p[n] = 1.f; }

  const int m0 = b*TLEN + chunk*TC;
  for (int i = 0; i < TC; i++) {
    const size_t m = m0 + i;
    float dtv = dt[m*D_INNER + d];
    float xv  = xc[m*D_INNER + d];
    float dbx = dtv * xv;
    const float4* Bp = (const float4*)(xdbl + m*NXDBL + DT_RANK);
    float4 B0 = Bp[0], B1 = Bp[1], B2 = Bp[2], B3 = Bp[3];
    float Bv[16] = {B0.x,B0.y,B0.z,B0.w, B1.x,B1.y,B1.z,B1.w,
                    B2.x,B2.y,B2.z,B2.w, B3.x,B3.y,B3.z,B3.w};
#pragma unroll
    for (int n = 0; n < 16; n++) {
      float dA = __expf(dtv * Ac[n]);
      h[n] = fmaf(dA, h[n], dbx * Bv[n]);
      p[n] *= dA;
    }
  }
  size_t o = ((size_t)((chunk*2 + b)*D_INNER + d))*D_STATE;
  float4* Pp = (float4*)(P + o);
  float4* Sp = (float4*)(S + o);
#pragma unroll
  for (int q = 0; q < 4; q++) {
    Pp[q] = (float4){p[q*4+0], p[q*4+1], p[q*4+2], p[q*4+3]};
    Sp[q] = (float4){h[q*4+0], h[q*4+1], h[q*4+2], h[q*4+3]};
  }
}

// ---------------- chunk-prefix stitch (in place: S[c] <- prefix state before chunk c) ----
__global__ __launch_bounds__(256) void stitch(
    const float* __restrict__ P, float* __restrict__ S)
{
  int idx = blockIdx.x*256 + threadIdx.x;   // (b*2048+d)*16+n, 65536 total
  const size_t stride = 2*D_INNER*D_STATE;
  float h = 0.f;
#pragma unroll 4
  for (int c = 0; c < NCHUNK; c++) {
    size_t o = (size_t)c*stride + idx;
    float p = P[o], s = S[o];
    S[o] = h;
    h = fmaf(p, h, s);
  }
}

// ---------------- scan pass2: recompute + y, fused silu(z)*y + D*x, bf16 out ----------------
__global__ __launch_bounds__(256) void scan2(
    const float* __restrict__ dt, const float* __restrict__ xc,
    const float* __restrict__ xdbl, const float* __restrict__ A_log,
    const float* __restrict__ Hpref, const float* __restrict__ xz,
    const float* __restrict__ Dp, u16* __restrict__ yb)
{
  const int bid = blockIdx.x;
  const int dblk = bid & 7;
  const int b = (bid >> 3) & 1;
  const int chunk = bid >> 4;
  const int d = dblk*256 + threadIdx.x;

  float Ac[16];
  {
    const float4* Ap = (const float4*)(A_log + (size_t)d*D_STATE);
#pragma unroll
    for (int q = 0; q < 4; q++) {
      float4 v = Ap[q];
      Ac[q*4+0] = -__expf(v.x); Ac[q*4+1] = -__expf(v.y);
      Ac[q*4+2] = -__expf(v.z); Ac[q*4+3] = -__expf(v.w);
    }
  }
  float h[16];
  {
    size_t o = ((size_t)((chunk*2 + b)*D_INNER + d))*D_STATE;
    const float4* Hp = (const float4*)(Hpref + o);
#pragma unroll
    for (int q = 0; q < 4; q++) {
      float4 v = Hp[q];
      h[q*4+0] = v.x; h[q*4+1] = v.y; h[q*4+2] = v.z; h[q*4+3] = v.w;
    }
  }
  const float Dv = Dp[d];
  const int m0 = b*TLEN + chunk*TC;
  for (int i = 0; i < TC; i++) {
    const size_t m = m0 + i;
    float dtv = dt[m*D_INNER + d];
    float xv  = xc[m*D_INNER + d];
    float dbx = dtv * xv;
    const float4* Bp = (const float4*)(xdbl + m*NXDBL + DT_RANK);
    float4 B0 = Bp[0], B1 = Bp[1], B2 = Bp[2], B3 = Bp[3];
    const float4* Cp = (const float4*)(xdbl + m*NXDBL + DT_RANK + D_STATE);
    float4 C0 = Cp[0], C1 = Cp[1], C2 = Cp[2], C3 = Cp[3];
    float Bv[16] = {B0.x,B0.y,B0.z,B0.w, B1.x,B1.y,B1.z,B1.w,
                    B2.x,B2.y,B2.z,B2.w, B3.x,B3.y,B3.z,B3.w};
    float Cv[16] = {C0.x,C0.y,C0.z,C0.w, C1.x,C1.y,C1.z,C1.w,
                    C2.x,C2.y,C2.z,C2.w, C3.x,C3.y,C3.z,C3.w};
    float y = 0.f;
#pragma unroll
    for (int n = 0; n < 16; n++) {
      float dA = __expf(dtv * Ac[n]);
      h[n] = fmaf(dA, h[n], dbx * Bv[n]);
      y = fmaf(h[n], Cv[n], y);
    }
    float z = xz[m*NXZ + D_INNER + d];
    float sz = z/(1.f + __expf(-z));
    yb[m*D_INNER + d] = f2bf(fmaf(y, sz, Dv*xv));
  }
}

// ---------------- launcher ----------------
extern "C" void kernel_launch(void* const* d_in, const int* in_sizes, int n_in,
                              void* d_out, int out_size, void* d_ws, size_t ws_size,
                              hipStream_t stream)
{
  const float* x     = (const float*)d_in[0];
  const float* W_in  = (const float*)d_in[1];
  const float* convw = (const float*)d_in[2];
  const float* convb = (const float*)d_in[3];
  const float* W_x   = (const float*)d_in[4];
  const float* W_dt  = (const float*)d_in[5];
  const float* b_dt  = (const float*)d_in[6];
  const float* A_log = (const float*)d_in[7];
  const float* Dp    = (const float*)d_in[8];
  const float* W_out = (const float*)d_in[9];
  float* out = (float*)d_out;

  char* w = (char*)d_ws;
  size_t o = 0;
  auto alloc = [&](size_t bytes) { char* p = w + o; o = (o + bytes + 255) & ~(size_t)255; return p; };
  u16*   xb   = (u16*)  alloc((size_t)M_TOK*D_MODEL*2);
  u16*   Wib  = (u16*)  alloc((size_t)NXZ*D_MODEL*2);
  u16*   Wxb  = (u16*)  alloc((size_t)NXDBL*D_INNER*2);
  u16*   Wdtb = (u16*)  alloc((size_t)D_INNER*DT_RANK*2);
  u16*   Wob  = (u16*)  alloc((size_t)D_MODEL*D_INNER*2);
  float* xzbuf= (float*)alloc((size_t)M_TOK*NXZ*4);
  float* xcf  = (float*)alloc((size_t)M_TOK*D_INNER*4);
  u16*   xcb  = (u16*)  alloc((size_t)M_TOK*D_INNER*2);
  float* part = (float*)alloc((size_t)8*M_TOK*NXDBL*4);
  float* xdbl = (float*)alloc((size_t)M_TOK*NXDBL*4);
  u16*   dtl  = (u16*)  alloc((size_t)M_TOK*DT_RANK*2);
  float* dtm  = (float*)alloc((size_t)M_TOK*D_INNER*4);
  float* Pb   = (float*)alloc((size_t)NCHUNK*2*D_INNER*D_STATE*4);
  float* Sb   = (float*)alloc((size_t)NCHUNK*2*D_INNER*D_STATE*4);
  u16*   yb   = (u16*)  alloc((size_t)M_TOK*D_INNER*2);
  (void)ws_size; (void)n_in; (void)in_sizes; (void)out_size;

  // 1. weight/input converts to bf16
  cvt_all<<<2048,256,0,stream>>>(x, xb, (M_TOK*D_MODEL)/4,
                                 W_in, Wib, (NXZ*D_MODEL)/4,
                                 W_dt, Wdtb, (D_INNER*DT_RANK)/4,
                                 W_out, Wob, (D_MODEL*D_INNER)/4);
  wx_pad<<<(NXDBL*D_INNER/4)/256,256,0,stream>>>(W_x, Wxb);
  // 2. xz = x @ W_in^T   (128x128 tile, 512 blocks)
  gemm_bt<0,4,4><<<dim3(M_TOK/128, NXZ/128, 1),256,0,stream>>>(xb, Wib, xzbuf, M_TOK, NXZ, D_MODEL, nullptr, D_MODEL);
  // 3. conv + silu
  conv_silu<<<(M_TOK*D_INNER)/256,256,0,stream>>>(xzbuf, convw, convb, xcf, xcb);
  // 4. x_dbl = x_conv @ W_x^T (64x64 tile, split-K 8 -> 512 blocks)
  gemm_bt<0,2,2><<<dim3(M_TOK/64, NXDBL/64, 8),256,0,stream>>>(xcb, Wxb, part, M_TOK, NXDBL, D_INNER, nullptr, D_INNER/8);
  prep<<<(M_TOK*NXDBL)/256,256,0,stream>>>(part, xdbl, dtl);
  // 5. dt = softplus(dt_low @ W_dt^T + b_dt)  (128x128 tile, 256 blocks)
  gemm_bt<1,4,4><<<dim3(M_TOK/128, D_INNER/128, 1),256,0,stream>>>(dtl, Wdtb, dtm, M_TOK, D_INNER, DT_RANK, b_dt, DT_RANK);
  // 6. chunked scan (d-per-lane): pass1 -> stitch (in-place prefix into Sb) -> pass2
  scan1<<<8*2*NCHUNK,256,0,stream>>>(dtm, xcf, xdbl, A_log, Pb, Sb);
  stitch<<<(2*D_INNER*D_STATE)/256,256,0,stream>>>(Pb, Sb);
  scan2<<<8*2*NCHUNK,256,0,stream>>>(dtm, xcf, xdbl, A_log, Sb, xzbuf, Dp, yb);
  // 7. out = y @ W_out^T  (64x64 tile, 512 blocks)
  gemm_bt<0,2,2><<<dim3(M_TOK/64, D_MODEL/64, 1),256,0,stream>>>(yb, Wob, out, M_TOK, D_MODEL, D_INNER, nullptr, D_INNER);
}

// Round 9
// 258.181 us; speedup vs baseline: 1.4353x; 1.0358x over previous
//
#include <hip/hip_runtime.h>
#include <cstdint>

#define D_MODEL 1024
#define D_STATE 16
#define D_INNER 2048
#define DT_RANK 64
#define BSZ 2
#define TLEN 1024
#define M_TOK (BSZ*TLEN)      // 2048 tokens
#define NXZ (2*D_INNER)       // 4096
#define NXDBL 128             // 96 padded to 128
#define TC 16
#define NCHUNK (TLEN/TC)      // 64

typedef unsigned short u16;
typedef short s16x8 __attribute__((ext_vector_type(8)));
typedef float f32x4 __attribute__((ext_vector_type(4)));

__device__ __forceinline__ u16 f2bf(float f) {
  uint32_t u = __float_as_uint(f);
  u += 0x7fffu + ((u >> 16) & 1u);
  return (u16)(u >> 16);
}

#define GLDS16(g, l) __builtin_amdgcn_global_load_lds( \
    (const __attribute__((address_space(1))) void*)(g), \
    (__attribute__((address_space(3))) void*)(l), 16, 0, 0)

// ---------------- converts ----------------
__global__ __launch_bounds__(256) void cvt_all(
    const float* __restrict__ s0, u16* __restrict__ d0, int n0,
    const float* __restrict__ s1, u16* __restrict__ d1, int n1,
    const float* __restrict__ s2, u16* __restrict__ d2, int n2,
    const float* __restrict__ s3, u16* __restrict__ d3, int n3)
{
  int total = n0 + n1 + n2 + n3;  // quad counts
  for (int i = blockIdx.x*256 + threadIdx.x; i < total; i += gridDim.x*256) {
    const float* s; u16* d; int j = i;
    if (j < n0)            { s = s0; d = d0; }
    else if ((j -= n0) < n1) { s = s1; d = d1; }
    else if ((j -= n1) < n2) { s = s2; d = d2; }
    else                   { j -= n2; s = s3; d = d3; }
    float4 v = ((const float4*)s)[j];
    u16* dst = d + (size_t)j*4;
    dst[0] = f2bf(v.x); dst[1] = f2bf(v.y); dst[2] = f2bf(v.z); dst[3] = f2bf(v.w);
  }
}

// W_x (96,2048) -> bf16 padded to (128,2048), pad rows zero
__global__ __launch_bounds__(256) void wx_pad(const float* __restrict__ wx, u16* __restrict__ dst)
{
  int i = blockIdx.x*256 + threadIdx.x;       // quad index over 128*2048/4
  int row = i >> 9;                            // 512 quads per row
  u16* d = dst + (size_t)i*4;
  if (row < 96) {
    float4 v = ((const float4*)wx)[i];
    d[0] = f2bf(v.x); d[1] = f2bf(v.y); d[2] = f2bf(v.z); d[3] = f2bf(v.w);
  } else {
    d[0] = 0; d[1] = 0; d[2] = 0; d[3] = 0;
  }
}

// ---------------- GEMM: C[m,n] = sum_k A[m,k]*B[n,k], bf16 in, f32 out ----------------
// Tile = (32*FM) x (32*FN); 4 waves in a 2x2 grid, each owns (FM*16) x (FN*16).
// EPI 0: plain   EPI 1: softplus(v + bias[n])
template<int EPI, int FM, int FN>
__global__ __launch_bounds__(256) void gemm_bt(
    const u16* __restrict__ A, const u16* __restrict__ B,
    float* __restrict__ C, int M, int N, int K,
    const float* __restrict__ bias, int kchunk)
{
  constexpr int BMt = FM*32;
  constexpr int BNt = FN*32;
  constexpr int AOPS = BMt/16;          // 16-row staging blocks for A
  constexpr int TOPS = (BMt+BNt)/16;    // total staging blocks
  constexpr int NOPS = TOPS/4;          // per wave
  __shared__ __align__(16) u16 As[BMt*32];
  __shared__ __align__(16) u16 Bs[BNt*32];
  const int tid  = threadIdx.x;
  const int lane = tid & 63;
  const int wv   = tid >> 6;
  const int m0 = blockIdx.x * BMt;
  const int n0 = blockIdx.y * BNt;
  const int kb = blockIdx.z * kchunk;
  const int ke = kb + kchunk;
  const int wr = wv >> 1, wc = wv & 1;

  f32x4 acc[FM][FN];
#pragma unroll
  for (int i = 0; i < FM; i++)
#pragma unroll
    for (int j = 0; j < FN; j++) acc[i][j] = (f32x4){0.f,0.f,0.f,0.f};

  // staging assignments (wave-uniform dst, per-lane src)
  const int rl = lane >> 2;
  const int c8 = (lane & 3) * 8;
  const u16* srcs[NOPS];
  u16* dsts[NOPS];
#pragma unroll
  for (int t = 0; t < NOPS; t++) {
    int op = wv + t*4;
    if (op < AOPS) {
      srcs[t] = A + (size_t)(m0 + op*16 + rl)*K + c8;
      dsts[t] = &As[op*512];
    } else {
      srcs[t] = B + (size_t)(n0 + (op-AOPS)*16 + rl)*K + c8;
      dsts[t] = &Bs[(op-AOPS)*512];
    }
  }

  const int fr = lane & 15;
  const int ko = (lane >> 4) * 8;
  for (int k0 = kb; k0 < ke; k0 += 32) {
    __syncthreads();
#pragma unroll
    for (int t = 0; t < NOPS; t++) GLDS16(srcs[t] + k0, dsts[t]);
    __syncthreads();
    s16x8 af[FM], bfv[FN];
#pragma unroll
    for (int i = 0; i < FM; i++) af[i]  = *(const s16x8*)&As[(wr*FM*16 + i*16 + fr)*32 + ko];
#pragma unroll
    for (int j = 0; j < FN; j++) bfv[j] = *(const s16x8*)&Bs[(wc*FN*16 + j*16 + fr)*32 + ko];
#pragma unroll
    for (int i = 0; i < FM; i++)
#pragma unroll
      for (int j = 0; j < FN; j++)
        acc[i][j] = __builtin_amdgcn_mfma_f32_16x16x32_bf16(af[i], bfv[j], acc[i][j], 0, 0, 0);
  }

  float* Cb = C + (size_t)blockIdx.z * M * N;
  const int cr = (lane >> 4) * 4;
  const int cc = lane & 15;
#pragma unroll
  for (int i = 0; i < FM; i++) {
#pragma unroll
    for (int j = 0; j < FN; j++) {
      const int col = n0 + (wc*FN + j)*16 + cc;
      float bv = (EPI == 1) ? bias[col] : 0.f;
#pragma unroll
      for (int q = 0; q < 4; q++) {
        const int row = m0 + (wr*FM + i)*16 + cr + q;
        float v = acc[i][j][q];
        if (EPI == 1) { v += bv; v = (v > 20.f) ? v : log1pf(__expf(v)); }
        Cb[(size_t)row*N + col] = v;
      }
    }
  }
}

// ---------------- causal depthwise conv (k=4) + SiLU, float4-vectorized ----------------
__global__ __launch_bounds__(256) void conv_silu(
    const float* __restrict__ xz, const float* __restrict__ cw,
    const float* __restrict__ cb, float* __restrict__ xcf, u16* __restrict__ xcb)
{
  int j = blockIdx.x*256 + threadIdx.x;      // quad index: m*512 + d/4
  int d0 = (j & 511) * 4;
  int m = j >> 9;
  int t = m & (TLEN-1);
  const float4* cwp = (const float4*)(cw + (size_t)d0*4);
  float4 wr0 = cwp[0], wr1 = cwp[1], wr2 = cwp[2], wr3 = cwp[3];
  const float w0[4] = {wr0.x, wr0.y, wr0.z, wr0.w};
  const float w1[4] = {wr1.x, wr1.y, wr1.z, wr1.w};
  const float w2[4] = {wr2.x, wr2.y, wr2.z, wr2.w};
  const float w3[4] = {wr3.x, wr3.y, wr3.z, wr3.w};
  float4 acc = *(const float4*)(cb + d0);
#pragma unroll
  for (int jj = 0; jj < 4; jj++) {
    int tt = t - 3 + jj;
    if (tt >= 0) {
      float4 v = *(const float4*)(xz + (size_t)(m-3+jj)*NXZ + d0);
      acc.x = fmaf(w0[jj], v.x, acc.x);
      acc.y = fmaf(w1[jj], v.y, acc.y);
      acc.z = fmaf(w2[jj], v.z, acc.z);
      acc.w = fmaf(w3[jj], v.w, acc.w);
    }
  }
  float4 r;
  r.x = acc.x / (1.f + __expf(-acc.x));
  r.y = acc.y / (1.f + __expf(-acc.y));
  r.z = acc.z / (1.f + __expf(-acc.z));
  r.w = acc.w / (1.f + __expf(-acc.w));
  *(float4*)(xcf + (size_t)m*D_INNER + d0) = r;
  union { u16 u[4]; uint2 v; } o;
  o.u[0] = f2bf(r.x); o.u[1] = f2bf(r.y); o.u[2] = f2bf(r.z); o.u[3] = f2bf(r.w);
  *(uint2*)(xcb + (size_t)m*D_INNER + d0) = o.v;
}

// ---------------- reduce split-K partials of GEMM2, emit dt_low bf16 ----------------
__global__ __launch_bounds__(256) void prep(
    const float* __restrict__ part, float* __restrict__ xdbl, u16* __restrict__ dtl)
{
  int idx = blockIdx.x*256 + threadIdx.x;    // 2048*128
  float s = 0.f;
#pragma unroll
  for (int c = 0; c < 8; c++) s += part[(size_t)c*M_TOK*NXDBL + idx];
  xdbl[idx] = s;
  int col = idx & 127;
  if (col < DT_RANK) {
    int m = idx >> 7;
    dtl[(size_t)m*DT_RANK + col] = f2bf(s);
  }
}

// ---------------- selective scan pass1: per-chunk (P, S), d-per-lane, 16 states in regs ----
__global__ __launch_bounds__(256) void scan1(
    const float* __restrict__ dt, const float* __restrict__ xc,
    const float* __restrict__ xdbl, const float* __restrict__ A_log,
    float* __restrict__ P, float* __restrict__ S)
{
  const int bid = blockIdx.x;        // dblk(8) | b(2) | chunk(64)
  const int dblk = bid & 7;
  const int b = (bid >> 3) & 1;
  const int chunk = bid >> 4;
  const int d = dblk*256 + threadIdx.x;

  float Ac[16];
  {
    const float4* Ap = (const float4*)(A_log + (size_t)d*D_STATE);
#pragma unroll
    for (int q = 0; q < 4; q++) {
      float4 v = Ap[q];
      Ac[q*4+0] = -__expf(v.x); Ac[q*4+1] = -__expf(v.y);
      Ac[q*4+2] = -__expf(v.z); Ac[q*4+3] = -__expf(v.w);
    }
  }
  float h[16], p[16];
#pragma unroll
  for (int n = 0; n < 16; n++) { h[n] = 0.f; p[n] = 1.f; }

  const int m0 = b*TLEN + chunk*TC;
  for (int i = 0; i < TC; i++) {
    const size_t m = m0 + i;
    float dtv = dt[m*D_INNER + d];
    float xv  = xc[m*D_INNER + d];
    float dbx = dtv * xv;
    const float4* Bp = (const float4*)(xdbl + m*NXDBL + DT_RANK);
    float4 B0 = Bp[0], B1 = Bp[1], B2 = Bp[2], B3 = Bp[3];
    float Bv[16] = {B0.x,B0.y,B0.z,B0.w, B1.x,B1.y,B1.z,B1.w,
                    B2.x,B2.y,B2.z,B2.w, B3.x,B3.y,B3.z,B3.w};
#pragma unroll
    for (int n = 0; n < 16; n++) {
      float dA = __expf(dtv * Ac[n]);
      h[n] = fmaf(dA, h[n], dbx * Bv[n]);
      p[n] *= dA;
    }
  }
  size_t o = ((size_t)((chunk*2 + b)*D_INNER + d))*D_STATE;
  float4* Pp = (float4*)(P + o);
  float4* Sp = (float4*)(S + o);
#pragma unroll
  for (int q = 0; q < 4; q++) {
    Pp[q] = (float4){p[q*4+0], p[q*4+1], p[q*4+2], p[q*4+3]};
    Sp[q] = (float4){h[q*4+0], h[q*4+1], h[q*4+2], h[q*4+3]};
  }
}

// ---------------- chunk-prefix stitch (in place: S[c] <- prefix state before chunk c) ----
__global__ __launch_bounds__(256) void stitch(
    const float* __restrict__ P, float* __restrict__ S)
{
  int idx = blockIdx.x*256 + threadIdx.x;   // (b*2048+d)*16+n, 65536 total
  const size_t stride = 2*D_INNER*D_STATE;
  float h = 0.f;
#pragma unroll 4
  for (int c = 0; c < NCHUNK; c++) {
    size_t o = (size_t)c*stride + idx;
    float p = P[o], s = S[o];
    S[o] = h;
    h = fmaf(p, h, s);
  }
}

// ---------------- scan pass2: recompute + y, fused silu(z)*y + D*x, bf16 out ----------------
__global__ __launch_bounds__(256) void scan2(
    const float* __restrict__ dt, const float* __restrict__ xc,
    const float* __restrict__ xdbl, const float* __restrict__ A_log,
    const float* __restrict__ Hpref, const float* __restrict__ xz,
    const float* __restrict__ Dp, u16* __restrict__ yb)
{
  const int bid = blockIdx.x;
  const int dblk = bid & 7;
  const int b = (bid >> 3) & 1;
  const int chunk = bid >> 4;
  const int d = dblk*256 + threadIdx.x;

  float Ac[16];
  {
    const float4* Ap = (const float4*)(A_log + (size_t)d*D_STATE);
#pragma unroll
    for (int q = 0; q < 4; q++) {
      float4 v = Ap[q];
      Ac[q*4+0] = -__expf(v.x); Ac[q*4+1] = -__expf(v.y);
      Ac[q*4+2] = -__expf(v.z); Ac[q*4+3] = -__expf(v.w);
    }
  }
  float h[16];
  {
    size_t o = ((size_t)((chunk*2 + b)*D_INNER + d))*D_STATE;
    const float4* Hp = (const float4*)(Hpref + o);
#pragma unroll
    for (int q = 0; q < 4; q++) {
      float4 v = Hp[q];
      h[q*4+0] = v.x; h[q*4+1] = v.y; h[q*4+2] = v.z; h[q*4+3] = v.w;
    }
  }
  const float Dv = Dp[d];
  const int m0 = b*TLEN + chunk*TC;
  for (int i = 0; i < TC; i++) {
    const size_t m = m0 + i;
    float dtv = dt[m*D_INNER + d];
    float xv  = xc[m*D_INNER + d];
    float dbx = dtv * xv;
    const float4* Bp = (const float4*)(xdbl + m*NXDBL + DT_RANK);
    float4 B0 = Bp[0], B1 = Bp[1], B2 = Bp[2], B3 = Bp[3];
    const float4* Cp = (const float4*)(xdbl + m*NXDBL + DT_RANK + D_STATE);
    float4 C0 = Cp[0], C1 = Cp[1], C2 = Cp[2], C3 = Cp[3];
    float Bv[16] = {B0.x,B0.y,B0.z,B0.w, B1.x,B1.y,B1.z,B1.w,
                    B2.x,B2.y,B2.z,B2.w, B3.x,B3.y,B3.z,B3.w};
    float Cv[16] = {C0.x,C0.y,C0.z,C0.w, C1.x,C1.y,C1.z,C1.w,
                    C2.x,C2.y,C2.z,C2.w, C3.x,C3.y,C3.z,C3.w};
    float y = 0.f;
#pragma unroll
    for (int n = 0; n < 16; n++) {
      float dA = __expf(dtv * Ac[n]);
      h[n] = fmaf(dA, h[n], dbx * Bv[n]);
      y = fmaf(h[n], Cv[n], y);
    }
    float z = xz[m*NXZ + D_INNER + d];
    float sz = z/(1.f + __expf(-z));
    yb[m*D_INNER + d] = f2bf(fmaf(y, sz, Dv*xv));
  }
}

// ---------------- launcher ----------------
extern "C" void kernel_launch(void* const* d_in, const int* in_sizes, int n_in,
                              void* d_out, int out_size, void* d_ws, size_t ws_size,
                              hipStream_t stream)
{
  const float* x     = (const float*)d_in[0];
  const float* W_in  = (const float*)d_in[1];
  const float* convw = (const float*)d_in[2];
  const float* convb = (const float*)d_in[3];
  const float* W_x   = (const float*)d_in[4];
  const float* W_dt  = (const float*)d_in[5];
  const float* b_dt  = (const float*)d_in[6];
  const float* A_log = (const float*)d_in[7];
  const float* Dp    = (const float*)d_in[8];
  const float* W_out = (const float*)d_in[9];
  float* out = (float*)d_out;

  char* w = (char*)d_ws;
  size_t o = 0;
  auto alloc = [&](size_t bytes) { char* p = w + o; o = (o + bytes + 255) & ~(size_t)255; return p; };
  u16*   xb   = (u16*)  alloc((size_t)M_TOK*D_MODEL*2);
  u16*   Wib  = (u16*)  alloc((size_t)NXZ*D_MODEL*2);
  u16*   Wxb  = (u16*)  alloc((size_t)NXDBL*D_INNER*2);
  u16*   Wdtb = (u16*)  alloc((size_t)D_INNER*DT_RANK*2);
  u16*   Wob  = (u16*)  alloc((size_t)D_MODEL*D_INNER*2);
  float* xzbuf= (float*)alloc((size_t)M_TOK*NXZ*4);
  float* xcf  = (float*)alloc((size_t)M_TOK*D_INNER*4);
  u16*   xcb  = (u16*)  alloc((size_t)M_TOK*D_INNER*2);
  float* part = (float*)alloc((size_t)8*M_TOK*NXDBL*4);
  float* xdbl = (float*)alloc((size_t)M_TOK*NXDBL*4);
  u16*   dtl  = (u16*)  alloc((size_t)M_TOK*DT_RANK*2);
  float* dtm  = (float*)alloc((size_t)M_TOK*D_INNER*4);
  float* Pb   = (float*)alloc((size_t)NCHUNK*2*D_INNER*D_STATE*4);
  float* Sb   = (float*)alloc((size_t)NCHUNK*2*D_INNER*D_STATE*4);
  u16*   yb   = (u16*)  alloc((size_t)M_TOK*D_INNER*2);
  (void)ws_size; (void)n_in; (void)in_sizes; (void)out_size;

  // 1. weight/input converts to bf16
  cvt_all<<<2048,256,0,stream>>>(x, xb, (M_TOK*D_MODEL)/4,
                                 W_in, Wib, (NXZ*D_MODEL)/4,
                                 W_dt, Wdtb, (D_INNER*DT_RANK)/4,
                                 W_out, Wob, (D_MODEL*D_INNER)/4);
  wx_pad<<<(NXDBL*D_INNER/4)/256,256,0,stream>>>(W_x, Wxb);
  // 2. xz = x @ W_in^T   (64x128 tile -> 1024 blocks, 4/CU)
  gemm_bt<0,2,4><<<dim3(M_TOK/64, NXZ/128, 1),256,0,stream>>>(xb, Wib, xzbuf, M_TOK, NXZ, D_MODEL, nullptr, D_MODEL);
  // 3. conv + silu (float4)
  conv_silu<<<(M_TOK*D_INNER/4)/256,256,0,stream>>>(xzbuf, convw, convb, xcf, xcb);
  // 4. x_dbl = x_conv @ W_x^T (64x64 tile, split-K 8 -> 512 blocks)
  gemm_bt<0,2,2><<<dim3(M_TOK/64, NXDBL/64, 8),256,0,stream>>>(xcb, Wxb, part, M_TOK, NXDBL, D_INNER, nullptr, D_INNER/8);
  prep<<<(M_TOK*NXDBL)/256,256,0,stream>>>(part, xdbl, dtl);
  // 5. dt = softplus(dt_low @ W_dt^T + b_dt)  (64x64 tile -> 1024 blocks)
  gemm_bt<1,2,2><<<dim3(M_TOK/64, D_INNER/64, 1),256,0,stream>>>(dtl, Wdtb, dtm, M_TOK, D_INNER, DT_RANK, b_dt, DT_RANK);
  // 6. chunked scan (d-per-lane): pass1 -> stitch (in-place prefix into Sb) -> pass2
  scan1<<<8*2*NCHUNK,256,0,stream>>>(dtm, xcf, xdbl, A_log, Pb, Sb);
  stitch<<<(2*D_INNER*D_STATE)/256,256,0,stream>>>(Pb, Sb);
  scan2<<<8*2*NCHUNK,256,0,stream>>>(dtm, xcf, xdbl, A_log, Sb, xzbuf, Dp, yb);
  // 7. out = y @ W_out^T  (64x64 tile, 512 blocks)
  gemm_bt<0,2,2><<<dim3(M_TOK/64, D_MODEL/64, 1),256,0,stream>>>(yb, Wob, out, M_TOK, D_MODEL, D_INNER, nullptr, D_INNER);
}

// Round 11
// 252.339 us; speedup vs baseline: 1.4685x; 1.0232x over previous
//
#include <hip/hip_runtime.h>
#include <cstdint>

#define D_MODEL 1024
#define D_STATE 16
#define D_INNER 2048
#define DT_RANK 64
#define BSZ 2
#define TLEN 1024
#define M_TOK (BSZ*TLEN)      // 2048 tokens
#define NXZ (2*D_INNER)       // 4096
#define NXDBL 128             // 96 padded to 128
#define TC 16
#define NCHUNK (TLEN/TC)      // 64

typedef unsigned short u16;
typedef short s16x8 __attribute__((ext_vector_type(8)));
typedef float f32x4 __attribute__((ext_vector_type(4)));

__device__ __forceinline__ u16 f2bf(float f) {
  uint32_t u = __float_as_uint(f);
  u += 0x7fffu + ((u >> 16) & 1u);
  return (u16)(u >> 16);
}
__device__ __forceinline__ float bf2f(u16 u) {
  return __uint_as_float(((uint32_t)u) << 16);
}

#define GLDS16(g, l) __builtin_amdgcn_global_load_lds( \
    (const __attribute__((address_space(1))) void*)(g), \
    (__attribute__((address_space(3))) void*)(l), 16, 0, 0)

// ---------------- converts ----------------
__global__ __launch_bounds__(256) void cvt_all(
    const float* __restrict__ s0, u16* __restrict__ d0, int n0,
    const float* __restrict__ s1, u16* __restrict__ d1, int n1,
    const float* __restrict__ s2, u16* __restrict__ d2, int n2,
    const float* __restrict__ s3, u16* __restrict__ d3, int n3)
{
  int total = n0 + n1 + n2 + n3;  // quad counts
  for (int i = blockIdx.x*256 + threadIdx.x; i < total; i += gridDim.x*256) {
    const float* s; u16* d; int j = i;
    if (j < n0)            { s = s0; d = d0; }
    else if ((j -= n0) < n1) { s = s1; d = d1; }
    else if ((j -= n1) < n2) { s = s2; d = d2; }
    else                   { j -= n2; s = s3; d = d3; }
    float4 v = ((const float4*)s)[j];
    u16* dst = d + (size_t)j*4;
    dst[0] = f2bf(v.x); dst[1] = f2bf(v.y); dst[2] = f2bf(v.z); dst[3] = f2bf(v.w);
  }
}

// W_x (96,2048) -> bf16 padded to (128,2048), pad rows zero
__global__ __launch_bounds__(256) void wx_pad(const float* __restrict__ wx, u16* __restrict__ dst)
{
  int i = blockIdx.x*256 + threadIdx.x;       // quad index over 128*2048/4
  int row = i >> 9;                            // 512 quads per row
  u16* d = dst + (size_t)i*4;
  if (row < 96) {
    float4 v = ((const float4*)wx)[i];
    d[0] = f2bf(v.x); d[1] = f2bf(v.y); d[2] = f2bf(v.z); d[3] = f2bf(v.w);
  } else {
    d[0] = 0; d[1] = 0; d[2] = 0; d[3] = 0;
  }
}

// ---------------- GEMM: C[m,n] = sum_k A[m,k]*B[n,k], bf16 in ----------------
// Tile = (32*FM) x (32*FN); 4 waves in a 2x2 grid, each owns (FM*16) x (FN*16).
// EPI 0: plain   EPI 1: softplus(v + bias[n])
// OBF 0: fp32 out   OBF 1: bf16 out
template<int EPI, int FM, int FN, int OBF>
__global__ __launch_bounds__(256) void gemm_bt(
    const u16* __restrict__ A, const u16* __restrict__ B,
    void* __restrict__ Cv, int M, int N, int K,
    const float* __restrict__ bias, int kchunk)
{
  constexpr int BMt = FM*32;
  constexpr int BNt = FN*32;
  constexpr int AOPS = BMt/16;          // 16-row staging blocks for A
  constexpr int TOPS = (BMt+BNt)/16;    // total staging blocks
  constexpr int NOPS = TOPS/4;          // per wave
  __shared__ __align__(16) u16 As[BMt*32];
  __shared__ __align__(16) u16 Bs[BNt*32];
  const int tid  = threadIdx.x;
  const int lane = tid & 63;
  const int wv   = tid >> 6;
  const int m0 = blockIdx.x * BMt;
  const int n0 = blockIdx.y * BNt;
  const int kb = blockIdx.z * kchunk;
  const int ke = kb + kchunk;
  const int wr = wv >> 1, wc = wv & 1;

  f32x4 acc[FM][FN];
#pragma unroll
  for (int i = 0; i < FM; i++)
#pragma unroll
    for (int j = 0; j < FN; j++) acc[i][j] = (f32x4){0.f,0.f,0.f,0.f};

  // staging assignments (wave-uniform dst, per-lane src)
  const int rl = lane >> 2;
  const int c8 = (lane & 3) * 8;
  const u16* srcs[NOPS];
  u16* dsts[NOPS];
#pragma unroll
  for (int t = 0; t < NOPS; t++) {
    int op = wv + t*4;
    if (op < AOPS) {
      srcs[t] = A + (size_t)(m0 + op*16 + rl)*K + c8;
      dsts[t] = &As[op*512];
    } else {
      srcs[t] = B + (size_t)(n0 + (op-AOPS)*16 + rl)*K + c8;
      dsts[t] = &Bs[(op-AOPS)*512];
    }
  }

  const int fr = lane & 15;
  const int ko = (lane >> 4) * 8;
  for (int k0 = kb; k0 < ke; k0 += 32) {
    __syncthreads();
#pragma unroll
    for (int t = 0; t < NOPS; t++) GLDS16(srcs[t] + k0, dsts[t]);
    __syncthreads();
    s16x8 af[FM], bfv[FN];
#pragma unroll
    for (int i = 0; i < FM; i++) af[i]  = *(const s16x8*)&As[(wr*FM*16 + i*16 + fr)*32 + ko];
#pragma unroll
    for (int j = 0; j < FN; j++) bfv[j] = *(const s16x8*)&Bs[(wc*FN*16 + j*16 + fr)*32 + ko];
#pragma unroll
    for (int i = 0; i < FM; i++)
#pragma unroll
      for (int j = 0; j < FN; j++)
        acc[i][j] = __builtin_amdgcn_mfma_f32_16x16x32_bf16(af[i], bfv[j], acc[i][j], 0, 0, 0);
  }

  float* Cf = (float*)Cv + (size_t)blockIdx.z * M * N;
  u16*   Ch = (u16*)Cv;
  const int cr = (lane >> 4) * 4;
  const int cc = lane & 15;
#pragma unroll
  for (int i = 0; i < FM; i++) {
#pragma unroll
    for (int j = 0; j < FN; j++) {
      const int col = n0 + (wc*FN + j)*16 + cc;
      float bv = (EPI == 1) ? bias[col] : 0.f;
#pragma unroll
      for (int q = 0; q < 4; q++) {
        const int row = m0 + (wr*FM + i)*16 + cr + q;
        float v = acc[i][j][q];
        if (EPI == 1) { v += bv; v = (v > 20.f) ? v : log1pf(__expf(v)); }
        if (OBF) Ch[(size_t)row*N + col] = f2bf(v);
        else     Cf[(size_t)row*N + col] = v;
      }
    }
  }
}

// ---------------- causal depthwise conv (k=4) + SiLU, bf16 in/out ----------------
__global__ __launch_bounds__(256) void conv_silu(
    const u16* __restrict__ xz, const float* __restrict__ cw,
    const float* __restrict__ cb, u16* __restrict__ xcb)
{
  int j = blockIdx.x*256 + threadIdx.x;      // quad index: m*512 + d/4
  int d0 = (j & 511) * 4;
  int m = j >> 9;
  int t = m & (TLEN-1);
  const float4* cwp = (const float4*)(cw + (size_t)d0*4);
  float4 wr0 = cwp[0], wr1 = cwp[1], wr2 = cwp[2], wr3 = cwp[3];
  const float w0[4] = {wr0.x, wr0.y, wr0.z, wr0.w};
  const float w1[4] = {wr1.x, wr1.y, wr1.z, wr1.w};
  const float w2[4] = {wr2.x, wr2.y, wr2.z, wr2.w};
  const float w3[4] = {wr3.x, wr3.y, wr3.z, wr3.w};
  float4 acc = *(const float4*)(cb + d0);
#pragma unroll
  for (int jj = 0; jj < 4; jj++) {
    int tt = t - 3 + jj;
    if (tt >= 0) {
      union { uint2 v; u16 u[4]; } ld;
      ld.v = *(const uint2*)(xz + (size_t)(m-3+jj)*NXZ + d0);
      acc.x = fmaf(w0[jj], bf2f(ld.u[0]), acc.x);
      acc.y = fmaf(w1[jj], bf2f(ld.u[1]), acc.y);
      acc.z = fmaf(w2[jj], bf2f(ld.u[2]), acc.z);
      acc.w = fmaf(w3[jj], bf2f(ld.u[3]), acc.w);
    }
  }
  float4 r;
  r.x = acc.x / (1.f + __expf(-acc.x));
  r.y = acc.y / (1.f + __expf(-acc.y));
  r.z = acc.z / (1.f + __expf(-acc.z));
  r.w = acc.w / (1.f + __expf(-acc.w));
  union { u16 u[4]; uint2 v; } o;
  o.u[0] = f2bf(r.x); o.u[1] = f2bf(r.y); o.u[2] = f2bf(r.z); o.u[3] = f2bf(r.w);
  *(uint2*)(xcb + (size_t)m*D_INNER + d0) = o.v;
}

// ---------------- reduce split-K partials of GEMM2, emit dt_low bf16 ----------------
__global__ __launch_bounds__(256) void prep(
    const float* __restrict__ part, float* __restrict__ xdbl, u16* __restrict__ dtl)
{
  int idx = blockIdx.x*256 + threadIdx.x;    // 2048*128
  float s = 0.f;
#pragma unroll
  for (int c = 0; c < 8; c++) s += part[(size_t)c*M_TOK*NXDBL + idx];
  xdbl[idx] = s;
  int col = idx & 127;
  if (col < DT_RANK) {
    int m = idx >> 7;
    dtl[(size_t)m*DT_RANK + col] = f2bf(s);
  }
}

// ---------------- selective scan pass1: per-chunk (P, S), d-per-lane, 16 states in regs ----
__global__ __launch_bounds__(256) void scan1(
    const u16* __restrict__ dt, const u16* __restrict__ xc,
    const float* __restrict__ xdbl, const float* __restrict__ A_log,
    float* __restrict__ P, float* __restrict__ S)
{
  const int bid = blockIdx.x;        // dblk(8) | b(2) | chunk(64)
  const int dblk = bid & 7;
  const int b = (bid >> 3) & 1;
  const int chunk = bid >> 4;
  const int d = dblk*256 + threadIdx.x;

  float Ac[16];
  {
    const float4* Ap = (const float4*)(A_log + (size_t)d*D_STATE);
#pragma unroll
    for (int q = 0; q < 4; q++) {
      float4 v = Ap[q];
      Ac[q*4+0] = -__expf(v.x); Ac[q*4+1] = -__expf(v.y);
      Ac[q*4+2] = -__expf(v.z); Ac[q*4+3] = -__expf(v.w);
    }
  }
  float h[16], p[16];
#pragma unroll
  for (int n = 0; n < 16; n++) { h[n] = 0.f; p[n] = 1.f; }

  const int m0 = b*TLEN + chunk*TC;
  for (int i = 0; i < TC; i++) {
    const size_t m = m0 + i;
    float dtv = bf2f(dt[m*D_INNER + d]);
    float xv  = bf2f(xc[m*D_INNER + d]);
    float dbx = dtv * xv;
    const float4* Bp = (const float4*)(xdbl + m*NXDBL + DT_RANK);
    float4 B0 = Bp[0], B1 = Bp[1], B2 = Bp[2], B3 = Bp[3];
    float Bv[16] = {B0.x,B0.y,B0.z,B0.w, B1.x,B1.y,B1.z,B1.w,
                    B2.x,B2.y,B2.z,B2.w, B3.x,B3.y,B3.z,B3.w};
#pragma unroll
    for (int n = 0; n < 16; n++) {
      float dA = __expf(dtv * Ac[n]);
      h[n] = fmaf(dA, h[n], dbx * Bv[n]);
      p[n] *= dA;
    }
  }
  size_t o = ((size_t)((chunk*2 + b)*D_INNER + d))*D_STATE;
  float4* Pp = (float4*)(P + o);
  float4* Sp = (float4*)(S + o);
#pragma unroll
  for (int q = 0; q < 4; q++) {
    Pp[q] = (float4){p[q*4+0], p[q*4+1], p[q*4+2], p[q*4+3]};
    Sp[q] = (float4){h[q*4+0], h[q*4+1], h[q*4+2], h[q*4+3]};
  }
}

// ---------------- chunk-prefix stitch (in place: S[c] <- prefix state before chunk c) ----
__global__ __launch_bounds__(256) void stitch(
    const float* __restrict__ P, float* __restrict__ S)
{
  int idx = blockIdx.x*256 + threadIdx.x;   // (b*2048+d)*16+n, 65536 total
  const size_t stride = 2*D_INNER*D_STATE;
  float h = 0.f;
#pragma unroll 4
  for (int c = 0; c < NCHUNK; c++) {
    size_t o = (size_t)c*stride + idx;
    float p = P[o], s = S[o];
    S[o] = h;
    h = fmaf(p, h, s);
  }
}

// ---------------- scan pass2: recompute + y, fused silu(z)*y + D*x, bf16 out ----------------
__global__ __launch_bounds__(256) void scan2(
    const u16* __restrict__ dt, const u16* __restrict__ xc,
    const float* __restrict__ xdbl, const float* __restrict__ A_log,
    const float* __restrict__ Hpref, const u16* __restrict__ xz,
    const float* __restrict__ Dp, u16* __restrict__ yb)
{
  const int bid = blockIdx.x;
  const int dblk = bid & 7;
  const int b = (bid >> 3) & 1;
  const int chunk = bid >> 4;
  const int d = dblk*256 + threadIdx.x;

  float Ac[16];
  {
    const float4* Ap = (const float4*)(A_log + (size_t)d*D_STATE);
#pragma unroll
    for (int q = 0; q < 4; q++) {
      float4 v = Ap[q];
      Ac[q*4+0] = -__expf(v.x); Ac[q*4+1] = -__expf(v.y);
      Ac[q*4+2] = -__expf(v.z); Ac[q*4+3] = -__expf(v.w);
    }
  }
  float h[16];
  {
    size_t o = ((size_t)((chunk*2 + b)*D_INNER + d))*D_STATE;
    const float4* Hp = (const float4*)(Hpref + o);
#pragma unroll
    for (int q = 0; q < 4; q++) {
      float4 v = Hp[q];
      h[q*4+0] = v.x; h[q*4+1] = v.y; h[q*4+2] = v.z; h[q*4+3] = v.w;
    }
  }
  const float Dv = Dp[d];
  const int m0 = b*TLEN + chunk*TC;
  for (int i = 0; i < TC; i++) {
    const size_t m = m0 + i;
    float dtv = bf2f(dt[m*D_INNER + d]);
    float xv  = bf2f(xc[m*D_INNER + d]);
    float dbx = dtv * xv;
    const float4* Bp = (const float4*)(xdbl + m*NXDBL + DT_RANK);
    float4 B0 = Bp[0], B1 = Bp[1], B2 = Bp[2], B3 = Bp[3];
    const float4* Cp = (const float4*)(xdbl + m*NXDBL + DT_RANK + D_STATE);
    float4 C0 = Cp[0], C1 = Cp[1], C2 = Cp[2], C3 = Cp[3];
    float Bv[16] = {B0.x,B0.y,B0.z,B0.w, B1.x,B1.y,B1.z,B1.w,
                    B2.x,B2.y,B2.z,B2.w, B3.x,B3.y,B3.z,B3.w};
    float Cv[16] = {C0.x,C0.y,C0.z,C0.w, C1.x,C1.y,C1.z,C1.w,
                    C2.x,C2.y,C2.z,C2.w, C3.x,C3.y,C3.z,C3.w};
    float y = 0.f;
#pragma unroll
    for (int n = 0; n < 16; n++) {
      float dA = __expf(dtv * Ac[n]);
      h[n] = fmaf(dA, h[n], dbx * Bv[n]);
      y = fmaf(h[n], Cv[n], y);
    }
    float z = bf2f(xz[m*NXZ + D_INNER + d]);
    float sz = z/(1.f + __expf(-z));
    yb[m*D_INNER + d] = f2bf(fmaf(y, sz, Dv*xv));
  }
}

// ---------------- launcher ----------------
extern "C" void kernel_launch(void* const* d_in, const int* in_sizes, int n_in,
                              void* d_out, int out_size, void* d_ws, size_t ws_size,
                              hipStream_t stream)
{
  const float* x     = (const float*)d_in[0];
  const float* W_in  = (const float*)d_in[1];
  const float* convw = (const float*)d_in[2];
  const float* convb = (const float*)d_in[3];
  const float* W_x   = (const float*)d_in[4];
  const float* W_dt  = (const float*)d_in[5];
  const float* b_dt  = (const float*)d_in[6];
  const float* A_log = (const float*)d_in[7];
  const float* Dp    = (const float*)d_in[8];
  const float* W_out = (const float*)d_in[9];
  float* out = (float*)d_out;

  char* w = (char*)d_ws;
  size_t o = 0;
  auto alloc = [&](size_t bytes) { char* p = w + o; o = (o + bytes + 255) & ~(size_t)255; return p; };
  u16*   xb   = (u16*)  alloc((size_t)M_TOK*D_MODEL*2);
  u16*   Wib  = (u16*)  alloc((size_t)NXZ*D_MODEL*2);
  u16*   Wxb  = (u16*)  alloc((size_t)NXDBL*D_INNER*2);
  u16*   Wdtb = (u16*)  alloc((size_t)D_INNER*DT_RANK*2);
  u16*   Wob  = (u16*)  alloc((size_t)D_MODEL*D_INNER*2);
  u16*   xzb  = (u16*)  alloc((size_t)M_TOK*NXZ*2);      // bf16 xz
  u16*   xcb  = (u16*)  alloc((size_t)M_TOK*D_INNER*2);  // bf16 x_conv
  float* part = (float*)alloc((size_t)8*M_TOK*NXDBL*4);
  float* xdbl = (float*)alloc((size_t)M_TOK*NXDBL*4);
  u16*   dtl  = (u16*)  alloc((size_t)M_TOK*DT_RANK*2);
  u16*   dtb  = (u16*)  alloc((size_t)M_TOK*D_INNER*2);  // bf16 dt
  float* Pb   = (float*)alloc((size_t)NCHUNK*2*D_INNER*D_STATE*4);
  float* Sb   = (float*)alloc((size_t)NCHUNK*2*D_INNER*D_STATE*4);
  u16*   yb   = (u16*)  alloc((size_t)M_TOK*D_INNER*2);
  (void)ws_size; (void)n_in; (void)in_sizes; (void)out_size;

  // 1. weight/input converts to bf16
  cvt_all<<<2048,256,0,stream>>>(x, xb, (M_TOK*D_MODEL)/4,
                                 W_in, Wib, (NXZ*D_MODEL)/4,
                                 W_dt, Wdtb, (D_INNER*DT_RANK)/4,
                                 W_out, Wob, (D_MODEL*D_INNER)/4);
  wx_pad<<<(NXDBL*D_INNER/4)/256,256,0,stream>>>(W_x, Wxb);
  // 2. xz = x @ W_in^T   (64x128 tile -> 1024 blocks; bf16 out)
  gemm_bt<0,2,4,1><<<dim3(M_TOK/64, NXZ/128, 1),256,0,stream>>>(xb, Wib, xzb, M_TOK, NXZ, D_MODEL, nullptr, D_MODEL);
  // 3. conv + silu (bf16 in/out)
  conv_silu<<<(M_TOK*D_INNER/4)/256,256,0,stream>>>(xzb, convw, convb, xcb);
  // 4. x_dbl = x_conv @ W_x^T (64x64 tile, split-K 8 -> 512 blocks; fp32 partials)
  gemm_bt<0,2,2,0><<<dim3(M_TOK/64, NXDBL/64, 8),256,0,stream>>>(xcb, Wxb, part, M_TOK, NXDBL, D_INNER, nullptr, D_INNER/8);
  prep<<<(M_TOK*NXDBL)/256,256,0,stream>>>(part, xdbl, dtl);
  // 5. dt = softplus(dt_low @ W_dt^T + b_dt)  (64x64 tile -> 1024 blocks; bf16 out)
  gemm_bt<1,2,2,1><<<dim3(M_TOK/64, D_INNER/64, 1),256,0,stream>>>(dtl, Wdtb, dtb, M_TOK, D_INNER, DT_RANK, b_dt, DT_RANK);
  // 6. chunked scan (d-per-lane): pass1 -> stitch (in-place prefix into Sb) -> pass2
  scan1<<<8*2*NCHUNK,256,0,stream>>>(dtb, xcb, xdbl, A_log, Pb, Sb);
  stitch<<<(2*D_INNER*D_STATE)/256,256,0,stream>>>(Pb, Sb);
  scan2<<<8*2*NCHUNK,256,0,stream>>>(dtb, xcb, xdbl, A_log, Sb, xzb, Dp, yb);
  // 7. out = y @ W_out^T  (64x64 tile, 512 blocks; fp32 out)
  gemm_bt<0,2,2,0><<<dim3(M_TOK/64, D_MODEL/64, 1),256,0,stream>>>(yb, Wob, out, M_TOK, D_MODEL, D_INNER, nullptr, D_INNER);
}

// Round 14
// 248.086 us; speedup vs baseline: 1.4937x; 1.0171x over previous
//
#include <hip/hip_runtime.h>
#include <cstdint>

#define D_MODEL 1024
#define D_STATE 16
#define D_INNER 2048
#define DT_RANK 64
#define BSZ 2
#define TLEN 1024
#define M_TOK (BSZ*TLEN)      // 2048 tokens
#define NXZ (2*D_INNER)       // 4096
#define NXDBL 128             // 96 padded to 128
#define TC 16
#define NCHUNK (TLEN/TC)      // 64

typedef unsigned short u16;
typedef short s16x8 __attribute__((ext_vector_type(8)));
typedef float f32x4 __attribute__((ext_vector_type(4)));

__device__ __forceinline__ u16 f2bf(float f) {
  uint32_t u = __float_as_uint(f);
  u += 0x7fffu + ((u >> 16) & 1u);
  return (u16)(u >> 16);
}
__device__ __forceinline__ float bf2f(u16 u) {
  return __uint_as_float(((uint32_t)u) << 16);
}

#define GLDS16(g, l) __builtin_amdgcn_global_load_lds( \
    (const __attribute__((address_space(1))) void*)(g), \
    (__attribute__((address_space(3))) void*)(l), 16, 0, 0)

// ---------------- converts (incl. W_x pad as source 4) ----------------
__global__ __launch_bounds__(256) void cvt_all(
    const float* __restrict__ s0, u16* __restrict__ d0, int n0,
    const float* __restrict__ s1, u16* __restrict__ d1, int n1,
    const float* __restrict__ s2, u16* __restrict__ d2, int n2,
    const float* __restrict__ s3, u16* __restrict__ d3, int n3,
    const float* __restrict__ s4, u16* __restrict__ d4, int n4)
{
  int total = n0 + n1 + n2 + n3 + n4;  // quad counts
  for (int i = blockIdx.x*256 + threadIdx.x; i < total; i += gridDim.x*256) {
    const float* s; u16* d; int j = i; bool pad = false;
    if (j < n0)              { s = s0; d = d0; }
    else if ((j -= n0) < n1) { s = s1; d = d1; }
    else if ((j -= n1) < n2) { s = s2; d = d2; }
    else if ((j -= n2) < n3) { s = s3; d = d3; }
    else { j -= n3; s = s4; d = d4; pad = ((j >> 9) >= 96); }  // W_x: 512 quads/row, rows>=96 zero
    u16* dst = d + (size_t)j*4;
    if (pad) { dst[0] = 0; dst[1] = 0; dst[2] = 0; dst[3] = 0; }
    else {
      float4 v = ((const float4*)s)[j];
      dst[0] = f2bf(v.x); dst[1] = f2bf(v.y); dst[2] = f2bf(v.z); dst[3] = f2bf(v.w);
    }
  }
}

// ---------------- GEMM: C[m,n] = sum_k A[m,k]*B[n,k], bf16 in ----------------
// Tile = (32*FM) x (32*FN); 4 waves in a 2x2 grid, each owns (FM*16) x (FN*16).
// EPI 0: plain   EPI 1: softplus(v + bias[n])
// OBF 0: fp32 out   OBF 1: bf16 out
template<int EPI, int FM, int FN, int OBF>
__global__ __launch_bounds__(256) void gemm_bt(
    const u16* __restrict__ A, const u16* __restrict__ B,
    void* __restrict__ Cv, int M, int N, int K,
    const float* __restrict__ bias, int kchunk)
{
  constexpr int BMt = FM*32;
  constexpr int BNt = FN*32;
  constexpr int AOPS = BMt/16;          // 16-row staging blocks for A
  constexpr int TOPS = (BMt+BNt)/16;    // total staging blocks
  constexpr int NOPS = TOPS/4;          // per wave
  __shared__ __align__(16) u16 As[BMt*32];
  __shared__ __align__(16) u16 Bs[BNt*32];
  const int tid  = threadIdx.x;
  const int lane = tid & 63;
  const int wv   = tid >> 6;
  const int m0 = blockIdx.x * BMt;
  const int n0 = blockIdx.y * BNt;
  const int kb = blockIdx.z * kchunk;
  const int ke = kb + kchunk;
  const int wr = wv >> 1, wc = wv & 1;

  f32x4 acc[FM][FN];
#pragma unroll
  for (int i = 0; i < FM; i++)
#pragma unroll
    for (int j = 0; j < FN; j++) acc[i][j] = (f32x4){0.f,0.f,0.f,0.f};

  // staging assignments (wave-uniform dst, per-lane src)
  const int rl = lane >> 2;
  const int c8 = (lane & 3) * 8;
  const u16* srcs[NOPS];
  u16* dsts[NOPS];
#pragma unroll
  for (int t = 0; t < NOPS; t++) {
    int op = wv + t*4;
    if (op < AOPS) {
      srcs[t] = A + (size_t)(m0 + op*16 + rl)*K + c8;
      dsts[t] = &As[op*512];
    } else {
      srcs[t] = B + (size_t)(n0 + (op-AOPS)*16 + rl)*K + c8;
      dsts[t] = &Bs[(op-AOPS)*512];
    }
  }

  const int fr = lane & 15;
  const int ko = (lane >> 4) * 8;
  for (int k0 = kb; k0 < ke; k0 += 32) {
    __syncthreads();
#pragma unroll
    for (int t = 0; t < NOPS; t++) GLDS16(srcs[t] + k0, dsts[t]);
    __syncthreads();
    s16x8 af[FM], bfv[FN];
#pragma unroll
    for (int i = 0; i < FM; i++) af[i]  = *(const s16x8*)&As[(wr*FM*16 + i*16 + fr)*32 + ko];
#pragma unroll
    for (int j = 0; j < FN; j++) bfv[j] = *(const s16x8*)&Bs[(wc*FN*16 + j*16 + fr)*32 + ko];
#pragma unroll
    for (int i = 0; i < FM; i++)
#pragma unroll
      for (int j = 0; j < FN; j++)
        acc[i][j] = __builtin_amdgcn_mfma_f32_16x16x32_bf16(af[i], bfv[j], acc[i][j], 0, 0, 0);
  }

  float* Cf = (float*)Cv + (size_t)blockIdx.z * M * N;
  u16*   Ch = (u16*)Cv;
  const int cr = (lane >> 4) * 4;
  const int cc = lane & 15;
#pragma unroll
  for (int i = 0; i < FM; i++) {
#pragma unroll
    for (int j = 0; j < FN; j++) {
      const int col = n0 + (wc*FN + j)*16 + cc;
      float bv = (EPI == 1) ? bias[col] : 0.f;
#pragma unroll
      for (int q = 0; q < 4; q++) {
        const int row = m0 + (wr*FM + i)*16 + cr + q;
        float v = acc[i][j][q];
        if (EPI == 1) { v += bv; v = (v > 20.f) ? v : log1pf(__expf(v)); }
        if (OBF) Ch[(size_t)row*N + col] = f2bf(v);
        else     Cf[(size_t)row*N + col] = v;
      }
    }
  }
}

// ---------------- causal depthwise conv (k=4) + SiLU, bf16 in/out ----------------
__global__ __launch_bounds__(256) void conv_silu(
    const u16* __restrict__ xz, const float* __restrict__ cw,
    const float* __restrict__ cb, u16* __restrict__ xcb)
{
  int j = blockIdx.x*256 + threadIdx.x;      // quad index: m*512 + d/4
  int d0 = (j & 511) * 4;
  int m = j >> 9;
  int t = m & (TLEN-1);
  const float4* cwp = (const float4*)(cw + (size_t)d0*4);
  float4 wr0 = cwp[0], wr1 = cwp[1], wr2 = cwp[2], wr3 = cwp[3];
  const float w0[4] = {wr0.x, wr0.y, wr0.z, wr0.w};
  const float w1[4] = {wr1.x, wr1.y, wr1.z, wr1.w};
  const float w2[4] = {wr2.x, wr2.y, wr2.z, wr2.w};
  const float w3[4] = {wr3.x, wr3.y, wr3.z, wr3.w};
  float4 acc = *(const float4*)(cb + d0);
#pragma unroll
  for (int jj = 0; jj < 4; jj++) {
    int tt = t - 3 + jj;
    if (tt >= 0) {
      union { uint2 v; u16 u[4]; } ld;
      ld.v = *(const uint2*)(xz + (size_t)(m-3+jj)*NXZ + d0);
      acc.x = fmaf(w0[jj], bf2f(ld.u[0]), acc.x);
      acc.y = fmaf(w1[jj], bf2f(ld.u[1]), acc.y);
      acc.z = fmaf(w2[jj], bf2f(ld.u[2]), acc.z);
      acc.w = fmaf(w3[jj], bf2f(ld.u[3]), acc.w);
    }
  }
  float4 r;
  r.x = acc.x / (1.f + __expf(-acc.x));
  r.y = acc.y / (1.f + __expf(-acc.y));
  r.z = acc.z / (1.f + __expf(-acc.z));
  r.w = acc.w / (1.f + __expf(-acc.w));
  union { u16 u[4]; uint2 v; } o;
  o.u[0] = f2bf(r.x); o.u[1] = f2bf(r.y); o.u[2] = f2bf(r.z); o.u[3] = f2bf(r.w);
  *(uint2*)(xcb + (size_t)m*D_INNER + d0) = o.v;
}

// ---------------- reduce split-K partials: dt_low -> bf16, B/C -> dense bc[m][32] ----------------
__global__ __launch_bounds__(256) void prep(
    const float* __restrict__ part, float* __restrict__ bc, u16* __restrict__ dtl)
{
  int idx = blockIdx.x*256 + threadIdx.x;    // 2048*128
  int col = idx & 127;
  if (col >= DT_RANK + 2*D_STATE) return;    // cols 96..127 are padding
  float s = 0.f;
#pragma unroll
  for (int c = 0; c < 8; c++) s += part[(size_t)c*M_TOK*NXDBL + idx];
  int m = idx >> 7;
  if (col < DT_RANK) dtl[(size_t)m*DT_RANK + col] = f2bf(s);
  else               bc[(size_t)m*32 + (col - DT_RANK)] = s;
}

// ---------------- selective scan pass1: per-chunk (P, S), d-per-lane, B from LDS ----------------
__global__ __launch_bounds__(256) void scan1(
    const u16* __restrict__ dt, const u16* __restrict__ xc,
    const float* __restrict__ bc, const float* __restrict__ A_log,
    float* __restrict__ P, float* __restrict__ S)
{
  __shared__ float Bsh[TC*16];
  const int bid = blockIdx.x;        // dblk(8) | b(2) | chunk(64)
  const int dblk = bid & 7;
  const int b = (bid >> 3) & 1;
  const int chunk = bid >> 4;
  const int d = dblk*256 + threadIdx.x;
  const int m0 = b*TLEN + chunk*TC;

  // coop stage B rows for this chunk: TC*16 floats, 1 per thread
  {
    int r = threadIdx.x;             // step = r>>4, n = r&15
    Bsh[r] = bc[(size_t)(m0 + (r >> 4))*32 + (r & 15)];
  }

  float Ac[16];
  {
    const float4* Ap = (const float4*)(A_log + (size_t)d*D_STATE);
#pragma unroll
    for (int q = 0; q < 4; q++) {
      float4 v = Ap[q];
      Ac[q*4+0] = -__expf(v.x); Ac[q*4+1] = -__expf(v.y);
      Ac[q*4+2] = -__expf(v.z); Ac[q*4+3] = -__expf(v.w);
    }
  }
  float h[16], p[16];
#pragma unroll
  for (int n = 0; n < 16; n++) { h[n] = 0.f; p[n] = 1.f; }
  __syncthreads();

  for (int i = 0; i < TC; i++) {
    const size_t m = m0 + i;
    float dtv = bf2f(dt[m*D_INNER + d]);
    float xv  = bf2f(xc[m*D_INNER + d]);
    float dbx = dtv * xv;
#pragma unroll
    for (int n = 0; n < 16; n++) {
      float dA = __expf(dtv * Ac[n]);
      h[n] = fmaf(dA, h[n], dbx * Bsh[i*16 + n]);
      p[n] *= dA;
    }
  }
  size_t o = ((size_t)((chunk*2 + b)*D_INNER + d))*D_STATE;
  float4* Pp = (float4*)(P + o);
  float4* Sp = (float4*)(S + o);
#pragma unroll
  for (int q = 0; q < 4; q++) {
    Pp[q] = (float4){p[q*4+0], p[q*4+1], p[q*4+2], p[q*4+3]};
    Sp[q] = (float4){h[q*4+0], h[q*4+1], h[q*4+2], h[q*4+3]};
  }
}

// ---------------- chunk-prefix stitch (in place: S[c] <- prefix state before chunk c) ----
__global__ __launch_bounds__(256) void stitch(
    const float* __restrict__ P, float* __restrict__ S)
{
  int idx = blockIdx.x*256 + threadIdx.x;   // (b*2048+d)*16+n, 65536 total
  const size_t stride = 2*D_INNER*D_STATE;
  float h = 0.f;
#pragma unroll 4
  for (int c = 0; c < NCHUNK; c++) {
    size_t o = (size_t)c*stride + idx;
    float p = P[o], s = S[o];
    S[o] = h;
    h = fmaf(p, h, s);
  }
}

// ---------------- scan pass2: recompute + y, fused silu(z)*y + D*x, B/C from LDS ----------------
__global__ __launch_bounds__(256) void scan2(
    const u16* __restrict__ dt, const u16* __restrict__ xc,
    const float* __restrict__ bc, const float* __restrict__ A_log,
    const float* __restrict__ Hpref, const u16* __restrict__ xz,
    const float* __restrict__ Dp, u16* __restrict__ yb)
{
  __shared__ float BCsh[TC*32];
  const int bid = blockIdx.x;
  const int dblk = bid & 7;
  const int b = (bid >> 3) & 1;
  const int chunk = bid >> 4;
  const int d = dblk*256 + threadIdx.x;
  const int m0 = b*TLEN + chunk*TC;

  // coop stage B+C rows: TC*32 floats, 2 per thread (dense bc layout)
  {
    int r = threadIdx.x;
    BCsh[r]       = bc[(size_t)m0*32 + r];
    BCsh[r + 256] = bc[(size_t)m0*32 + r + 256];
  }

  float Ac[16];
  {
    const float4* Ap = (const float4*)(A_log + (size_t)d*D_STATE);
#pragma unroll
    for (int q = 0; q < 4; q++) {
      float4 v = Ap[q];
      Ac[q*4+0] = -__expf(v.x); Ac[q*4+1] = -__expf(v.y);
      Ac[q*4+2] = -__expf(v.z); Ac[q*4+3] = -__expf(v.w);
    }
  }
  float h[16];
  {
    size_t o = ((size_t)((chunk*2 + b)*D_INNER + d))*D_STATE;
    const float4* Hp = (const float4*)(Hpref + o);
#pragma unroll
    for (int q = 0; q < 4; q++) {
      float4 v = Hp[q];
      h[q*4+0] = v.x; h[q*4+1] = v.y; h[q*4+2] = v.z; h[q*4+3] = v.w;
    }
  }
  const float Dv = Dp[d];
  __syncthreads();

  for (int i = 0; i < TC; i++) {
    const size_t m = m0 + i;
    float dtv = bf2f(dt[m*D_INNER + d]);
    float xv  = bf2f(xc[m*D_INNER + d]);
    float dbx = dtv * xv;
    float y = 0.f;
#pragma unroll
    for (int n = 0; n < 16; n++) {
      float dA = __expf(dtv * Ac[n]);
      h[n] = fmaf(dA, h[n], dbx * BCsh[i*32 + n]);
      y = fmaf(h[n], BCsh[i*32 + 16 + n], y);
    }
    float z = bf2f(xz[m*NXZ + D_INNER + d]);
    float sz = z/(1.f + __expf(-z));
    yb[m*D_INNER + d] = f2bf(fmaf(y, sz, Dv*xv));
  }
}

// ---------------- launcher ----------------
extern "C" void kernel_launch(void* const* d_in, const int* in_sizes, int n_in,
                              void* d_out, int out_size, void* d_ws, size_t ws_size,
                              hipStream_t stream)
{
  const float* x     = (const float*)d_in[0];
  const float* W_in  = (const float*)d_in[1];
  const float* convw = (const float*)d_in[2];
  const float* convb = (const float*)d_in[3];
  const float* W_x   = (const float*)d_in[4];
  const float* W_dt  = (const float*)d_in[5];
  const float* b_dt  = (const float*)d_in[6];
  const float* A_log = (const float*)d_in[7];
  const float* Dp    = (const float*)d_in[8];
  const float* W_out = (const float*)d_in[9];
  float* out = (float*)d_out;

  char* w = (char*)d_ws;
  size_t o = 0;
  auto alloc = [&](size_t bytes) { char* p = w + o; o = (o + bytes + 255) & ~(size_t)255; return p; };
  u16*   xb   = (u16*)  alloc((size_t)M_TOK*D_MODEL*2);
  u16*   Wib  = (u16*)  alloc((size_t)NXZ*D_MODEL*2);
  u16*   Wxb  = (u16*)  alloc((size_t)NXDBL*D_INNER*2);
  u16*   Wdtb = (u16*)  alloc((size_t)D_INNER*DT_RANK*2);
  u16*   Wob  = (u16*)  alloc((size_t)D_MODEL*D_INNER*2);
  u16*   xzb  = (u16*)  alloc((size_t)M_TOK*NXZ*2);      // bf16 xz
  u16*   xcb  = (u16*)  alloc((size_t)M_TOK*D_INNER*2);  // bf16 x_conv
  float* part = (float*)alloc((size_t)8*M_TOK*NXDBL*4);
  float* bcb  = (float*)alloc((size_t)M_TOK*32*4);       // dense B/C fp32
  u16*   dtl  = (u16*)  alloc((size_t)M_TOK*DT_RANK*2);
  u16*   dtb  = (u16*)  alloc((size_t)M_TOK*D_INNER*2);  // bf16 dt
  float* Pb   = (float*)alloc((size_t)NCHUNK*2*D_INNER*D_STATE*4);
  float* Sb   = (float*)alloc((size_t)NCHUNK*2*D_INNER*D_STATE*4);
  u16*   yb   = (u16*)  alloc((size_t)M_TOK*D_INNER*2);
  (void)ws_size; (void)n_in; (void)in_sizes; (void)out_size;

  // 1. weight/input converts to bf16 (+ W_x pad)
  cvt_all<<<2048,256,0,stream>>>(x, xb, (M_TOK*D_MODEL)/4,
                                 W_in, Wib, (NXZ*D_MODEL)/4,
                                 W_dt, Wdtb, (D_INNER*DT_RANK)/4,
                                 W_out, Wob, (D_MODEL*D_INNER)/4,
                                 W_x, Wxb, (NXDBL*D_INNER)/4);
  // 2. xz = x @ W_in^T   (64x128 tile -> 1024 blocks; bf16 out)
  gemm_bt<0,2,4,1><<<dim3(M_TOK/64, NXZ/128, 1),256,0,stream>>>(xb, Wib, xzb, M_TOK, NXZ, D_MODEL, nullptr, D_MODEL);
  // 3. conv + silu (bf16 in/out)
  conv_silu<<<(M_TOK*D_INNER/4)/256,256,0,stream>>>(xzb, convw, convb, xcb);
  // 4. x_dbl = x_conv @ W_x^T (64x64 tile, split-K 8 -> 512 blocks; fp32 partials)
  gemm_bt<0,2,2,0><<<dim3(M_TOK/64, NXDBL/64, 8),256,0,stream>>>(xcb, Wxb, part, M_TOK, NXDBL, D_INNER, nullptr, D_INNER/8);
  prep<<<(M_TOK*NXDBL)/256,256,0,stream>>>(part, bcb, dtl);
  // 5. dt = softplus(dt_low @ W_dt^T + b_dt)  (64x64 tile -> 1024 blocks; bf16 out)
  gemm_bt<1,2,2,1><<<dim3(M_TOK/64, D_INNER/64, 1),256,0,stream>>>(dtl, Wdtb, dtb, M_TOK, D_INNER, DT_RANK, b_dt, DT_RANK);
  // 6. chunked scan (d-per-lane, B/C via LDS): pass1 -> stitch -> pass2
  scan1<<<8*2*NCHUNK,256,0,stream>>>(dtb, xcb, bcb, A_log, Pb, Sb);
  stitch<<<(2*D_INNER*D_STATE)/256,256,0,stream>>>(Pb, Sb);
  scan2<<<8*2*NCHUNK,256,0,stream>>>(dtb, xcb, bcb, A_log, Sb, xzb, Dp, yb);
  // 7. out = y @ W_out^T  (64x64 tile, 512 blocks; fp32 out)
  gemm_bt<0,2,2,0><<<dim3(M_TOK/64, D_MODEL/64, 1),256,0,stream>>>(yb, Wob, out, M_TOK, D_MODEL, D_INNER, nullptr, D_INNER);
}